// Round 14
// baseline (1958.016 us; speedup 1.0000x reference)
//
#include <hip/hip_runtime.h>
#include <hip/hip_bf16.h>
#include <cmath>
#include <cstdint>

#define B_  2
#define T_  1024
#define V_  32000
#define D_  1024
#define H_  16
#define L_  8
#define DH_ 64

typedef __attribute__((ext_vector_type(8))) short bf16x8;
typedef __attribute__((ext_vector_type(4))) float f32x4;

__device__ __forceinline__ ushort f2bf(float f) {
    union { float f; uint32_t u; } v; v.f = f;
    uint32_t r = v.u + 0x7FFFu + ((v.u >> 16) & 1u);
    return (ushort)(r >> 16);
}
__device__ __forceinline__ float bf2f(ushort u) {
    union { uint32_t u; float f; } v; v.u = ((uint32_t)u) << 16;
    return v.f;
}

__device__ __forceinline__ void async_copy16(const void* g, void* l) {
    __builtin_amdgcn_global_load_lds(
        (const __attribute__((address_space(1))) void*)g,
        (__attribute__((address_space(3))) void*)l, 16, 0, 0);
}

// ---------------- fp32 -> bf16 cast (weights) ----------------
__global__ __launch_bounds__(256) void k_cast(const float4* __restrict__ in,
                                              ushort4* __restrict__ out, int n4) {
    for (int i = blockIdx.x * 256 + threadIdx.x; i < n4; i += gridDim.x * 256) {
        float4 v = in[i];
        out[i] = make_ushort4(f2bf(v.x), f2bf(v.y), f2bf(v.z), f2bf(v.w));
    }
}

// ---------------- RoPE tables: cos/sin (T, 32) ----------------
__global__ void k_rope_tables(float* __restrict__ cosT, float* __restrict__ sinT) {
    int t = blockIdx.x;
    int i = threadIdx.x;           // 0..31
    float invf = (i < 16) ? powf(1000.0f, -(float)i / 16.0f) : 0.0f;
    float th = (float)t * invf;
    cosT[t * 32 + i] = cosf(th);
    sinT[t * 32 + i] = sinf(th);
}

// ---------------- Embedding gather (fp32 x) ----------------
__global__ __launch_bounds__(256) void k_gather(const int* __restrict__ idx,
                                                const float* __restrict__ emb,
                                                float* __restrict__ x) {
    int row = blockIdx.x;
    int id = idx[row];
    const float4* src = (const float4*)(emb + (size_t)id * D_);
    float4* dst = (float4*)(x + (size_t)row * D_);
    dst[threadIdx.x] = src[threadIdx.x];
}

// ---------------- RMSNorm: bf16 out ----------------
__global__ __launch_bounds__(256) void k_rmsnorm(const float* __restrict__ x,
                                                 ushort* __restrict__ out) {
    int row = blockIdx.x;
    const float4* xr = (const float4*)(x + (size_t)row * D_);
    float4 v = xr[threadIdx.x];
    float ss = v.x * v.x + v.y * v.y + v.z * v.z + v.w * v.w;
    #pragma unroll
    for (int off = 1; off < 64; off <<= 1) ss += __shfl_xor(ss, off);
    __shared__ float wsum[4];
    int lane = threadIdx.x & 63, wv = threadIdx.x >> 6;
    if (lane == 0) wsum[wv] = ss;
    __syncthreads();
    float tot = wsum[0] + wsum[1] + wsum[2] + wsum[3];
    float inv = rsqrtf(tot * (1.0f / D_) + 1e-6f);
    ushort4 r = make_ushort4(f2bf(v.x * inv), f2bf(v.y * inv), f2bf(v.z * inv), f2bf(v.w * inv));
    *(ushort4*)(out + (size_t)row * D_ + threadIdx.x * 4) = r;
}

// ---------------- MFMA GEMM: BM=128, BK=64, T2 swizzle, T1 swizzle ----------------
// BN<=128: prefetch double-buffer. BN=256: single buffer, high-intensity (lm_head).
// EPI: 0 none(+nontemporal), 1 +Res(fp32), 2 relu^2, 3 RoPE(qkv).
template<int BN, int EPI, bool OUTBF, bool CONVB>
__global__ __launch_bounds__(256, 2) void k_mfma_gemm(const ushort* __restrict__ A,
                                                      const void* __restrict__ Wp,
                                                      void* __restrict__ Cp,
                                                      const float* __restrict__ Res,
                                                      const float* __restrict__ cosT,
                                                      const float* __restrict__ sinT,
                                                      int M, int N, int K) {
    constexpr int BM = 128;
    constexpr int MI = 4;
    constexpr int NI = BN / 32;
    constexpr bool DBUF = (BN <= 128);
    constexpr int NB = DBUF ? 2 : 1;
    __shared__ ushort As[NB][BM][64];   // swizzled: chunk c of row r at byte ((c^(r&7))<<4)
    __shared__ ushort Bs[NB][BN][64];
    const int tid = threadIdx.x;
    const int wid = tid >> 6, lane = tid & 63;
    const int wr = wid >> 1, wc = wid & 1;
    const int r16 = lane & 15, kc = lane >> 4;
    const int rx = (r16 & 7) << 4;
    const int srow8 = tid >> 3;
    const int sdcp = tid & 7;

    const int nwg = gridDim.x * gridDim.y;
    int orig = blockIdx.y * gridDim.x + blockIdx.x;
    int swz = (nwg & 7) ? orig : ((orig & 7) * (nwg >> 3) + (orig >> 3));
    const size_t bm = (size_t)(swz % gridDim.x) * BM;
    const size_t bn = (size_t)(swz / gridDim.x) * BN;

    auto stage = [&](int buf, int k0) {
        #pragma unroll
        for (int i = 0; i < 4; i++) {
            const int row = i * 32 + srow8;
            const ushort* g = A + (bm + row) * (size_t)K + k0 + ((sdcp ^ (row & 7)) * 8);
            async_copy16(g, (char*)As + buf * (BM * 128) + (i * 256 + tid) * 16);
        }
        if constexpr (!CONVB) {
            const ushort* Wb = (const ushort*)Wp;
            #pragma unroll
            for (int i = 0; i < BN / 32; i++) {
                const int row = i * 32 + srow8;
                const ushort* g = Wb + (bn + row) * (size_t)K + k0 + ((sdcp ^ (row & 7)) * 8);
                async_copy16(g, (char*)Bs + buf * (BN * 128) + (i * 256 + tid) * 16);
            }
        } else {
            const float* Wf = (const float*)Wp;
            #pragma unroll
            for (int i = 0; i < BN / 32; i++) {
                const int row = i * 32 + srow8;
                const float* src = Wf + (bn + row) * (size_t)K + k0 + sdcp * 8;
                float4 v0 = *(const float4*)(src);
                float4 v1 = *(const float4*)(src + 4);
                union { ushort u[8]; bf16x8 v; } tmp;
                tmp.u[0] = f2bf(v0.x); tmp.u[1] = f2bf(v0.y);
                tmp.u[2] = f2bf(v0.z); tmp.u[3] = f2bf(v0.w);
                tmp.u[4] = f2bf(v1.x); tmp.u[5] = f2bf(v1.y);
                tmp.u[6] = f2bf(v1.z); tmp.u[7] = f2bf(v1.w);
                *(bf16x8*)((char*)Bs + buf * (BN * 128) + row * 128 + ((sdcp ^ (row & 7)) << 4)) = tmp.v;
            }
        }
    };

    f32x4 acc[MI][NI];
    #pragma unroll
    for (int mi = 0; mi < MI; mi++)
        #pragma unroll
        for (int ni = 0; ni < NI; ni++) {
            f32x4 z = {0.f, 0.f, 0.f, 0.f};
            acc[mi][ni] = z;
        }

    auto compute = [&](int buf) {
        #pragma unroll
        for (int kk = 0; kk < 2; kk++) {
            bf16x8 af[MI], bfr[NI];
            #pragma unroll
            for (int mi = 0; mi < MI; mi++)
                af[mi] = *(const bf16x8*)((const char*)As + buf * (BM * 128) +
                                          (wr * 64 + mi * 16 + r16) * 128 +
                                          ((kk * 64 + kc * 16) ^ rx));
            #pragma unroll
            for (int ni = 0; ni < NI; ni++)
                bfr[ni] = *(const bf16x8*)((const char*)Bs + buf * (BN * 128) +
                                           (wc * (BN / 2) + ni * 16 + r16) * 128 +
                                           ((kk * 64 + kc * 16) ^ rx));
            #pragma unroll
            for (int mi = 0; mi < MI; mi++)
                #pragma unroll
                for (int ni = 0; ni < NI; ni++)
                    acc[mi][ni] = __builtin_amdgcn_mfma_f32_16x16x32_bf16(af[mi], bfr[ni],
                                                                          acc[mi][ni], 0, 0, 0);
        }
    };

    const int KSTEPS = K >> 6;
    if constexpr (DBUF) {
        stage(0, 0);
        __syncthreads();
        for (int step = 0; step < KSTEPS; ++step) {
            const int cur = step & 1;
            if (step + 1 < KSTEPS) stage(cur ^ 1, (step + 1) << 6);
            compute(cur);
            __syncthreads();
        }
    } else {
        for (int step = 0; step < KSTEPS; ++step) {
            stage(0, step << 6);
            __syncthreads();
            compute(0);
            __syncthreads();
        }
    }

    #pragma unroll
    for (int mi = 0; mi < MI; mi++) {
        #pragma unroll
        for (int j = 0; j < 4; j++) {
            const size_t row = bm + wr * 64 + mi * 16 + (lane >> 4) * 4 + j;
            if constexpr (EPI == 3) {
                static_assert(BN == 128, "rope epilogue assumes BN=128");
                const int sec = (int)((bn + wc * 64) >> 10);   // 0=q,1=k,2=v
                if (sec < 2) {
                    const int t = (int)(row & (T_ - 1));
                    #pragma unroll
                    for (int np = 0; np < 2; np++) {
                        const int i1 = np * 16 + r16;          // 0..31
                        float c = cosT[t * 32 + i1], s = sinT[t * 32 + i1];
                        float x1 = acc[mi][np][j], x2 = acc[mi][np + 2][j];
                        acc[mi][np][j]     = c * x1 - s * x2;
                        acc[mi][np + 2][j] = s * x1 + c * x2;
                    }
                }
            }
            #pragma unroll
            for (int ni = 0; ni < NI; ni++) {
                const size_t col = bn + wc * (BN / 2) + ni * 16 + r16;
                float v = acc[mi][ni][j];
                if constexpr (EPI == 1) v += Res[row * N + col];
                if constexpr (EPI == 2) { v = fmaxf(v, 0.f); v *= v; }
                if constexpr (OUTBF) {
                    ((ushort*)Cp)[row * N + col] = f2bf(v);
                } else if constexpr (EPI == 0) {
                    __builtin_nontemporal_store(v, (float*)Cp + row * N + col);
                } else {
                    ((float*)Cp)[row * N + col] = v;
                }
            }
        }
    }
}

// ---------------- Split-KV flash attention ----------------
// Block = (q-tile qt, KV-half hf) of one (b,h). 1024 blocks x 256 thr, 24KB LDS
// -> 4 blocks/CU. Each block processes a contiguous half of the chunk range and
// writes unnormalized partials (o, m, l); k_attn_comb merges the two halves.
__global__ __launch_bounds__(256) void k_attn_split(const ushort* __restrict__ qkv,
                                                    float* __restrict__ po,
                                                    float* __restrict__ pml) {
    __shared__ __align__(16) char lds[24576];
    // [0,8K): K[64key][64d] swz | [8K,16K): Vt[64d][64key] swz | [16K,24K): Q/P
    const int tid = threadIdx.x;
    const int w = tid >> 6, lane = tid & 63;
    const int r16 = lane & 15, kc = lane >> 4;
    const int rx = (r16 & 7) << 4;
    const int qt = blockIdx.x >> 1, hf = blockIdx.x & 1;
    const int qb = qt * 64;
    const int bh = blockIdx.y, b = bh >> 4, h = bh & 15;
    const size_t tok0 = (size_t)b * T_;
    const ushort* kg = qkv + tok0 * (3 * D_) + D_ + h * DH_;
    const ushort* vg = qkv + tok0 * (3 * D_) + 2 * D_ + h * DH_;
    const float SCALE_LOG2E = 0.125f * 1.44269504089f;

    const int nch = qt + 1;
    const int mid = (nch + 1) >> 1;
    const int ch0 = hf ? mid : 0;
    const int ch1 = hf ? nch : mid;

    // stage Q (swizzled source, linear LDS dest)
    {
        const ushort* qg = qkv + (tok0 + qb) * (3 * D_) + h * DH_;
        #pragma unroll
        for (int i = 0; i < 2; i++) {
            int slot = i * 256 + tid;
            int row = slot >> 3, dcp = slot & 7;
            int d0 = (dcp ^ (row & 7)) * 8;
            async_copy16(qg + (size_t)row * (3 * D_) + d0, lds + 16384 + slot * 16);
        }
    }
    __syncthreads();
    bf16x8 aq[2];
    #pragma unroll
    for (int ks = 0; ks < 2; ks++) {
        int row = w * 16 + r16;
        aq[ks] = *(const bf16x8*)(lds + 16384 + row * 128 + ((ks * 64 + kc * 16) ^ rx));
    }

    f32x4 o[4];
    float m[4], l[4], corr[4];
    #pragma unroll
    for (int nd = 0; nd < 4; nd++) { f32x4 z = {0.f, 0.f, 0.f, 0.f}; o[nd] = z; }
    #pragma unroll
    for (int j = 0; j < 4; j++) { m[j] = -1e30f; l[j] = 0.f; }

    for (int ch = ch0; ch < ch1; ch++) {
        const int kb = ch << 6;
        __syncthreads();
        // stage K (64 keys x 64 d)
        #pragma unroll
        for (int i = 0; i < 2; i++) {
            int slot = i * 256 + tid;
            int row = slot >> 3, dcp = slot & 7;
            int d0 = (dcp ^ (row & 7)) * 8;
            async_copy16(kg + (size_t)(kb + row) * (3 * D_) + d0, lds + slot * 16);
        }
        // stage Vt (transposed, reg-staged)
        {
            int key = tid >> 2, dbase = (tid & 3) * 16;
            const ushort* src = vg + (size_t)(kb + key) * (3 * D_) + dbase;
            bf16x8 v0 = *(const bf16x8*)(src);
            bf16x8 v1 = *(const bf16x8*)(src + 8);
            #pragma unroll
            for (int e = 0; e < 8; e++) {
                int d = dbase + e;
                *(ushort*)(lds + 8192 + d * 128 + ((key * 2) ^ ((d & 7) << 4))) = (ushort)v0[e];
                d = dbase + 8 + e;
                *(ushort*)(lds + 8192 + d * 128 + ((key * 2) ^ ((d & 7) << 4))) = (ushort)v1[e];
            }
        }
        __syncthreads();

        // S = Q K^T (64 q x 64 k)
        f32x4 s[4];
        #pragma unroll
        for (int ni = 0; ni < 4; ni++) { f32x4 z = {0.f, 0.f, 0.f, 0.f}; s[ni] = z; }
        __builtin_amdgcn_s_setprio(1);
        #pragma unroll
        for (int ks = 0; ks < 2; ks++)
            #pragma unroll
            for (int ni = 0; ni < 4; ni++) {
                int row = ni * 16 + r16;
                bf16x8 kf = *(const bf16x8*)(lds + row * 128 + ((ks * 64 + kc * 16) ^ rx));
                s[ni] = __builtin_amdgcn_mfma_f32_16x16x32_bf16(aq[ks], kf, s[ni], 0, 0, 0);
            }
        __builtin_amdgcn_s_setprio(0);

        const bool diag = (kb == qb);
        #pragma unroll
        for (int j = 0; j < 4; j++) {
            const int qrow = qb + w * 16 + kc * 4 + j;
            #pragma unroll
            for (int ni = 0; ni < 4; ni++) {
                float v = s[ni][j] * SCALE_LOG2E;
                if (diag) { int key = kb + ni * 16 + r16; if (key > qrow) v = -1e30f; }
                s[ni][j] = v;
            }
            float tmax = fmaxf(fmaxf(s[0][j], s[1][j]), fmaxf(s[2][j], s[3][j]));
            #pragma unroll
            for (int off = 1; off < 16; off <<= 1) tmax = fmaxf(tmax, __shfl_xor(tmax, off));
            float mn = fmaxf(m[j], tmax);
            corr[j] = exp2f(m[j] - mn);
            m[j] = mn;
            float ps = 0.f;
            #pragma unroll
            for (int ni = 0; ni < 4; ni++) {
                float p = exp2f(s[ni][j] - mn);
                s[ni][j] = p;
                ps += p;
            }
            #pragma unroll
            for (int off = 1; off < 16; off <<= 1) ps += __shfl_xor(ps, off);
            l[j] = l[j] * corr[j] + ps;
        }
        // P -> LDS bf16 (own wave's rows)
        #pragma unroll
        for (int ni = 0; ni < 4; ni++)
            #pragma unroll
            for (int j = 0; j < 4; j++) {
                int row = w * 16 + kc * 4 + j;
                *(ushort*)(lds + 16384 + row * 128 + ((ni * 32 + r16 * 2) ^ ((row & 7) << 4))) = f2bf(s[ni][j]);
            }
        // rescale O
        #pragma unroll
        for (int nd = 0; nd < 4; nd++)
            #pragma unroll
            for (int j = 0; j < 4; j++) o[nd][j] *= corr[j];
        // O += P V
        __builtin_amdgcn_s_setprio(1);
        #pragma unroll
        for (int ks = 0; ks < 2; ks++) {
            int prow = w * 16 + r16;
            bf16x8 pf = *(const bf16x8*)(lds + 16384 + prow * 128 + ((ks * 64 + kc * 16) ^ rx));
            #pragma unroll
            for (int nd = 0; nd < 4; nd++) {
                int drow = nd * 16 + r16;
                bf16x8 vf = *(const bf16x8*)(lds + 8192 + drow * 128 + ((ks * 64 + kc * 16) ^ rx));
                o[nd] = __builtin_amdgcn_mfma_f32_16x16x32_bf16(pf, vf, o[nd], 0, 0, 0);
            }
        }
        __builtin_amdgcn_s_setprio(0);
    }

    // write unnormalized partials
    const int tix = (bh * 16 + qt) * 2 + hf;
    float* pob = po + (size_t)tix * 4096;
    #pragma unroll
    for (int j = 0; j < 4; j++) {
        const int row = w * 16 + kc * 4 + j;
        #pragma unroll
        for (int nd = 0; nd < 4; nd++)
            pob[row * 64 + nd * 16 + r16] = o[nd][j];
        if (r16 == 0) {
            pml[(size_t)tix * 128 + row * 2]     = m[j];
            pml[(size_t)tix * 128 + row * 2 + 1] = l[j];
        }
    }
}

// ---------------- combine the two KV-halves -> ctx (bf16) ----------------
__global__ __launch_bounds__(256) void k_attn_comb(const float* __restrict__ po,
                                                   const float* __restrict__ pml,
                                                   ushort* __restrict__ ctx) {
    const int qt = blockIdx.x, bh = blockIdx.y, b = bh >> 4, h = bh & 15;
    const int t0 = (bh * 16 + qt) * 2;
    const int row = threadIdx.x >> 2;            // 0..63
    const int c0 = (threadIdx.x & 3) * 16;       // col base
    const float m0 = pml[(size_t)t0 * 128 + row * 2];
    const float l0 = pml[(size_t)t0 * 128 + row * 2 + 1];
    const float m1 = pml[(size_t)(t0 + 1) * 128 + row * 2];
    const float l1 = pml[(size_t)(t0 + 1) * 128 + row * 2 + 1];
    const float M = fmaxf(m0, m1);
    const float w0 = exp2f(m0 - M), w1 = exp2f(m1 - M);
    const float inv = 1.0f / (l0 * w0 + l1 * w1);
    const float* p0 = po + (size_t)t0 * 4096 + row * 64 + c0;
    const float* p1 = po + (size_t)(t0 + 1) * 4096 + row * 64 + c0;
    ushort* dst = ctx + ((size_t)b * T_ + qt * 64 + row) * D_ + h * DH_ + c0;
    #pragma unroll
    for (int i = 0; i < 4; i++) {
        float4 a = *(const float4*)(p0 + i * 4);
        float4 bb = *(const float4*)(p1 + i * 4);
        ushort4 r = make_ushort4(f2bf((a.x * w0 + bb.x * w1) * inv),
                                 f2bf((a.y * w0 + bb.y * w1) * inv),
                                 f2bf((a.z * w0 + bb.z * w1) * inv),
                                 f2bf((a.w * w0 + bb.w * w1) * inv));
        *(ushort4*)(dst + i * 4) = r;
    }
}

extern "C" void kernel_launch(void* const* d_in, const int* in_sizes, int n_in,
                              void* d_out, int out_size, void* d_ws, size_t ws_size,
                              hipStream_t stream) {
    const int*   xi   = (const int*)d_in[0];
    const float* emb  = (const float*)d_in[1];
    const float* Wqkv = (const float*)d_in[2];
    const float* Wout = (const float*)d_in[3];
    const float* W1   = (const float*)d_in[4];
    const float* W2   = (const float*)d_in[5];
    const float* lmh  = (const float*)d_in[6];
    float* out = (float*)d_out;

    const size_t NT = (size_t)B_ * T_;
    size_t off = 0;
    auto carve = [&](size_t bytes) -> char* {
        char* r = (char*)d_ws + off;
        off += (bytes + 255) & ~(size_t)255;
        return r;
    };
    float*  xbuf = (float*)carve(NT * D_ * 4);
    ushort* qkv  = (ushort*)carve(NT * 3 * D_ * 2);
    ushort* nb   = (ushort*)carve(NT * D_ * 2);
    ushort* ctxb = (ushort*)carve(NT * D_ * 2);
    ushort* hb   = (ushort*)carve(NT * 4 * D_ * 2);
    float*  cosT = (float*)carve(T_ * 32 * 4);
    float*  sinT = (float*)carve(T_ * 32 * 4);
    float*  po   = (float*)carve((size_t)B_ * H_ * 16 * 2 * 4096 * 4);  // 16 MB partial O
    float*  pml  = (float*)carve((size_t)B_ * H_ * 16 * 2 * 128 * 4);   // partial m,l

    const size_t nWqkv = (size_t)L_ * 3 * D_ * D_;
    const size_t nWout = (size_t)L_ * D_ * D_;
    const size_t nW1   = (size_t)L_ * 4 * D_ * D_;
    const size_t nW2   = (size_t)L_ * 4 * D_ * D_;
    const size_t nLmh  = (size_t)V_ * D_;
    ushort* WqkvB = (ushort*)carve(nWqkv * 2);
    ushort* WoutB = (ushort*)carve(nWout * 2);
    ushort* W1B   = (ushort*)carve(nW1 * 2);
    ushort* W2B   = (ushort*)carve(nW2 * 2);
    ushort* lmhB  = (ushort*)carve(nLmh * 2);
    const bool preconv = (off <= ws_size);

    if (preconv) {
        k_cast<<<dim3(2048), dim3(256), 0, stream>>>((const float4*)Wqkv, (ushort4*)WqkvB, (int)(nWqkv / 4));
        k_cast<<<dim3(2048), dim3(256), 0, stream>>>((const float4*)Wout, (ushort4*)WoutB, (int)(nWout / 4));
        k_cast<<<dim3(2048), dim3(256), 0, stream>>>((const float4*)W1,   (ushort4*)W1B,   (int)(nW1 / 4));
        k_cast<<<dim3(2048), dim3(256), 0, stream>>>((const float4*)W2,   (ushort4*)W2B,   (int)(nW2 / 4));
        k_cast<<<dim3(2048), dim3(256), 0, stream>>>((const float4*)lmh,  (ushort4*)lmhB,  (int)(nLmh / 4));
    }

#define LAUNCH_GEMM(BN, EPI, OUTBF, GX, GY, Aq, Wb16, Wf32, Cq, Rq, Mv, Nv, Kv)              \
    do {                                                                                     \
        if (preconv)                                                                         \
            k_mfma_gemm<BN, EPI, OUTBF, false><<<dim3(GX, GY), dim3(256), 0, stream>>>(      \
                (const ushort*)(Aq), (const void*)(Wb16), (void*)(Cq), (Rq), cosT, sinT,     \
                Mv, Nv, Kv);                                                                 \
        else                                                                                 \
            k_mfma_gemm<BN, EPI, OUTBF, true><<<dim3(GX, GY), dim3(256), 0, stream>>>(       \
                (const ushort*)(Aq), (const void*)(Wf32), (void*)(Cq), (Rq), cosT, sinT,     \
                Mv, Nv, Kv);                                                                 \
    } while (0)

    k_rope_tables<<<dim3(T_), dim3(32), 0, stream>>>(cosT, sinT);
    k_gather<<<dim3(NT), dim3(256), 0, stream>>>(xi, emb, xbuf);

    for (int l = 0; l < L_; l++) {
        k_rmsnorm<<<dim3(NT), dim3(256), 0, stream>>>(xbuf, nb);
        LAUNCH_GEMM(128, 3, true, 16, 24, nb,
                    WqkvB + (size_t)l * 3 * D_ * D_, Wqkv + (size_t)l * 3 * D_ * D_,
                    qkv, nullptr, (int)NT, 3 * D_, D_);
        k_attn_split<<<dim3(32, B_ * H_), dim3(256), 0, stream>>>(qkv, po, pml);
        k_attn_comb<<<dim3(16, B_ * H_), dim3(256), 0, stream>>>(po, pml, ctxb);
        LAUNCH_GEMM(64, 1, false, 16, 16, ctxb,
                    WoutB + (size_t)l * D_ * D_, Wout + (size_t)l * D_ * D_,
                    xbuf, xbuf, (int)NT, D_, D_);
        k_rmsnorm<<<dim3(NT), dim3(256), 0, stream>>>(xbuf, nb);
        LAUNCH_GEMM(128, 2, true, 16, 32, nb,
                    W1B + (size_t)l * 4 * D_ * D_, W1 + (size_t)l * 4 * D_ * D_,
                    hb, nullptr, (int)NT, 4 * D_, D_);
        LAUNCH_GEMM(64, 1, false, 16, 16, hb,
                    W2B + (size_t)l * 4 * D_ * D_, W2 + (size_t)l * 4 * D_ * D_,
                    xbuf, xbuf, (int)NT, D_, 4 * D_);
    }
    k_rmsnorm<<<dim3(NT), dim3(256), 0, stream>>>(xbuf, nb);
    LAUNCH_GEMM(256, 0, false, 16, 125, nb, lmhB, lmh, out, nullptr, (int)NT, V_, D_);
#undef LAUNCH_GEMM
}

// Round 15
// 1746.077 us; speedup vs baseline: 1.1214x; 1.1214x over previous
//
#include <hip/hip_runtime.h>
#include <hip/hip_bf16.h>
#include <cmath>
#include <cstdint>

#define B_  2
#define T_  1024
#define V_  32000
#define D_  1024
#define H_  16
#define L_  8
#define DH_ 64

typedef __attribute__((ext_vector_type(8))) short bf16x8;
typedef __attribute__((ext_vector_type(4))) float f32x4;

__device__ __forceinline__ ushort f2bf(float f) {
    union { float f; uint32_t u; } v; v.f = f;
    uint32_t r = v.u + 0x7FFFu + ((v.u >> 16) & 1u);
    return (ushort)(r >> 16);
}
__device__ __forceinline__ float bf2f(ushort u) {
    union { uint32_t u; float f; } v; v.u = ((uint32_t)u) << 16;
    return v.f;
}

__device__ __forceinline__ void async_copy16(const void* g, void* l) {
    __builtin_amdgcn_global_load_lds(
        (const __attribute__((address_space(1))) void*)g,
        (__attribute__((address_space(3))) void*)l, 16, 0, 0);
}

// ---------------- fp32 -> bf16 cast (weights) ----------------
__global__ __launch_bounds__(256) void k_cast(const float4* __restrict__ in,
                                              ushort4* __restrict__ out, int n4) {
    for (int i = blockIdx.x * 256 + threadIdx.x; i < n4; i += gridDim.x * 256) {
        float4 v = in[i];
        out[i] = make_ushort4(f2bf(v.x), f2bf(v.y), f2bf(v.z), f2bf(v.w));
    }
}

// ---------------- RoPE tables: cos/sin (T, 32) ----------------
__global__ void k_rope_tables(float* __restrict__ cosT, float* __restrict__ sinT) {
    int t = blockIdx.x;
    int i = threadIdx.x;           // 0..31
    float invf = (i < 16) ? powf(1000.0f, -(float)i / 16.0f) : 0.0f;
    float th = (float)t * invf;
    cosT[t * 32 + i] = cosf(th);
    sinT[t * 32 + i] = sinf(th);
}

// ---------------- Embedding gather (fp32 x) ----------------
__global__ __launch_bounds__(256) void k_gather(const int* __restrict__ idx,
                                                const float* __restrict__ emb,
                                                float* __restrict__ x) {
    int row = blockIdx.x;
    int id = idx[row];
    const float4* src = (const float4*)(emb + (size_t)id * D_);
    float4* dst = (float4*)(x + (size_t)row * D_);
    dst[threadIdx.x] = src[threadIdx.x];
}

// ---------------- RMSNorm: bf16 out ----------------
__global__ __launch_bounds__(256) void k_rmsnorm(const float* __restrict__ x,
                                                 ushort* __restrict__ out) {
    int row = blockIdx.x;
    const float4* xr = (const float4*)(x + (size_t)row * D_);
    float4 v = xr[threadIdx.x];
    float ss = v.x * v.x + v.y * v.y + v.z * v.z + v.w * v.w;
    #pragma unroll
    for (int off = 1; off < 64; off <<= 1) ss += __shfl_xor(ss, off);
    __shared__ float wsum[4];
    int lane = threadIdx.x & 63, wv = threadIdx.x >> 6;
    if (lane == 0) wsum[wv] = ss;
    __syncthreads();
    float tot = wsum[0] + wsum[1] + wsum[2] + wsum[3];
    float inv = rsqrtf(tot * (1.0f / D_) + 1e-6f);
    ushort4 r = make_ushort4(f2bf(v.x * inv), f2bf(v.y * inv), f2bf(v.z * inv), f2bf(v.w * inv));
    *(ushort4*)(out + (size_t)row * D_ + threadIdx.x * 4) = r;
}

// ---------------- MFMA GEMM: BM=128, BK=64, T2 swizzle, T1 swizzle ----------------
// BN<=128: prefetch double-buffer. BN=256: single buffer, high-intensity tile.
// EPI: 0 none(+nontemporal), 1 +Res(fp32), 2 relu^2, 3 RoPE(qkv), 4 atomicAdd(fp32).
// SPLITK: gridDim.z blocks each accumulate K/gridDim.z (use with EPI=4).
template<int BN, int EPI, bool OUTBF, bool CONVB, bool SPLITK>
__global__ __launch_bounds__(256, 2) void k_mfma_gemm(const ushort* __restrict__ A,
                                                      const void* __restrict__ Wp,
                                                      void* __restrict__ Cp,
                                                      const float* __restrict__ Res,
                                                      const float* __restrict__ cosT,
                                                      const float* __restrict__ sinT,
                                                      int M, int N, int K) {
    constexpr int BM = 128;
    constexpr int MI = 4;
    constexpr int NI = BN / 32;
    constexpr bool DBUF = (BN <= 128);
    constexpr int NB = DBUF ? 2 : 1;
    __shared__ ushort As[NB][BM][64];   // swizzled: chunk c of row r at byte ((c^(r&7))<<4)
    __shared__ ushort Bs[NB][BN][64];
    const int tid = threadIdx.x;
    const int wid = tid >> 6, lane = tid & 63;
    const int wr = wid >> 1, wc = wid & 1;
    const int r16 = lane & 15, kc = lane >> 4;
    const int rx = (r16 & 7) << 4;
    const int srow8 = tid >> 3;
    const int sdcp = tid & 7;

    const int nwg = gridDim.x * gridDim.y;
    int orig = blockIdx.y * gridDim.x + blockIdx.x;
    int swz = (nwg & 7) ? orig : ((orig & 7) * (nwg >> 3) + (orig >> 3));
    const size_t bm = (size_t)(swz % gridDim.x) * BM;
    const size_t bn = (size_t)(swz / gridDim.x) * BN;

    const int KSTEPS = SPLITK ? (K >> 7) : (K >> 6);
    const int kbase  = SPLITK ? (int)blockIdx.z * (K >> 1) : 0;

    auto stage = [&](int buf, int k0) {
        #pragma unroll
        for (int i = 0; i < 4; i++) {
            const int row = i * 32 + srow8;
            const ushort* g = A + (bm + row) * (size_t)K + k0 + ((sdcp ^ (row & 7)) * 8);
            async_copy16(g, (char*)As + buf * (BM * 128) + (i * 256 + tid) * 16);
        }
        if constexpr (!CONVB) {
            const ushort* Wb = (const ushort*)Wp;
            #pragma unroll
            for (int i = 0; i < BN / 32; i++) {
                const int row = i * 32 + srow8;
                const ushort* g = Wb + (bn + row) * (size_t)K + k0 + ((sdcp ^ (row & 7)) * 8);
                async_copy16(g, (char*)Bs + buf * (BN * 128) + (i * 256 + tid) * 16);
            }
        } else {
            const float* Wf = (const float*)Wp;
            #pragma unroll
            for (int i = 0; i < BN / 32; i++) {
                const int row = i * 32 + srow8;
                const float* src = Wf + (bn + row) * (size_t)K + k0 + sdcp * 8;
                float4 v0 = *(const float4*)(src);
                float4 v1 = *(const float4*)(src + 4);
                union { ushort u[8]; bf16x8 v; } tmp;
                tmp.u[0] = f2bf(v0.x); tmp.u[1] = f2bf(v0.y);
                tmp.u[2] = f2bf(v0.z); tmp.u[3] = f2bf(v0.w);
                tmp.u[4] = f2bf(v1.x); tmp.u[5] = f2bf(v1.y);
                tmp.u[6] = f2bf(v1.z); tmp.u[7] = f2bf(v1.w);
                *(bf16x8*)((char*)Bs + buf * (BN * 128) + row * 128 + ((sdcp ^ (row & 7)) << 4)) = tmp.v;
            }
        }
    };

    f32x4 acc[MI][NI];
    #pragma unroll
    for (int mi = 0; mi < MI; mi++)
        #pragma unroll
        for (int ni = 0; ni < NI; ni++) {
            f32x4 z = {0.f, 0.f, 0.f, 0.f};
            acc[mi][ni] = z;
        }

    auto compute = [&](int buf) {
        #pragma unroll
        for (int kk = 0; kk < 2; kk++) {
            bf16x8 af[MI], bfr[NI];
            #pragma unroll
            for (int mi = 0; mi < MI; mi++)
                af[mi] = *(const bf16x8*)((const char*)As + buf * (BM * 128) +
                                          (wr * 64 + mi * 16 + r16) * 128 +
                                          ((kk * 64 + kc * 16) ^ rx));
            #pragma unroll
            for (int ni = 0; ni < NI; ni++)
                bfr[ni] = *(const bf16x8*)((const char*)Bs + buf * (BN * 128) +
                                           (wc * (BN / 2) + ni * 16 + r16) * 128 +
                                           ((kk * 64 + kc * 16) ^ rx));
            #pragma unroll
            for (int mi = 0; mi < MI; mi++)
                #pragma unroll
                for (int ni = 0; ni < NI; ni++)
                    acc[mi][ni] = __builtin_amdgcn_mfma_f32_16x16x32_bf16(af[mi], bfr[ni],
                                                                          acc[mi][ni], 0, 0, 0);
        }
    };

    if constexpr (DBUF) {
        stage(0, kbase);
        __syncthreads();
        for (int step = 0; step < KSTEPS; ++step) {
            const int cur = step & 1;
            if (step + 1 < KSTEPS) stage(cur ^ 1, kbase + ((step + 1) << 6));
            compute(cur);
            __syncthreads();
        }
    } else {
        for (int step = 0; step < KSTEPS; ++step) {
            stage(0, kbase + (step << 6));
            __syncthreads();
            compute(0);
            __syncthreads();
        }
    }

    #pragma unroll
    for (int mi = 0; mi < MI; mi++) {
        #pragma unroll
        for (int j = 0; j < 4; j++) {
            const size_t row = bm + wr * 64 + mi * 16 + (lane >> 4) * 4 + j;
            if constexpr (EPI == 3) {
                static_assert(BN == 128, "rope epilogue assumes BN=128");
                const int sec = (int)((bn + wc * 64) >> 10);   // 0=q,1=k,2=v
                if (sec < 2) {
                    const int t = (int)(row & (T_ - 1));
                    #pragma unroll
                    for (int np = 0; np < 2; np++) {
                        const int i1 = np * 16 + r16;          // 0..31
                        float c = cosT[t * 32 + i1], s = sinT[t * 32 + i1];
                        float x1 = acc[mi][np][j], x2 = acc[mi][np + 2][j];
                        acc[mi][np][j]     = c * x1 - s * x2;
                        acc[mi][np + 2][j] = s * x1 + c * x2;
                    }
                }
            }
            #pragma unroll
            for (int ni = 0; ni < NI; ni++) {
                const size_t col = bn + wc * (BN / 2) + ni * 16 + r16;
                float v = acc[mi][ni][j];
                if constexpr (EPI == 1) v += Res[row * N + col];
                if constexpr (EPI == 2) { v = fmaxf(v, 0.f); v *= v; }
                if constexpr (EPI == 4) {
                    atomicAdd((float*)Cp + row * N + col, v);
                } else if constexpr (OUTBF) {
                    ((ushort*)Cp)[row * N + col] = f2bf(v);
                } else if constexpr (EPI == 0) {
                    __builtin_nontemporal_store(v, (float*)Cp + row * N + col);
                } else {
                    ((float*)Cp)[row * N + col] = v;
                }
            }
        }
    }
}

// ---------------- 8-wave paired flash attention, KVBLK=128 (R13, best) ----------------
__global__ __launch_bounds__(512) void k_attn_p8(const ushort* __restrict__ qkv,
                                                 ushort* __restrict__ ctx) {
    __shared__ __align__(16) char lds[65536];
    const int tid = threadIdx.x;
    const int w = tid >> 6, lane = tid & 63;
    const int r16 = lane & 15, kc = lane >> 4;
    const int rx = (r16 & 7) << 4;
    const int ip = blockIdx.x;                 // 0..7
    const int tw = w >> 2;                     // 0 = hi tile, 1 = lo tile
    const int wq = w & 3;
    const int hib = (15 - ip) * 64, lob = ip * 64;
    const int tb = tw ? lob : hib;
    const int pq = 32768 + tw * 16384;
    const int bh = blockIdx.y, b = bh >> 4, h = bh & 15;
    const size_t tok0 = (size_t)b * T_;
    const ushort* kg = qkv + tok0 * (3 * D_) + D_ + h * DH_;
    const ushort* vg = qkv + tok0 * (3 * D_) + 2 * D_ + h * DH_;
    const float SCALE_LOG2E = 0.125f * 1.44269504089f;

    {
        const int bases[2] = { hib, lob };
        #pragma unroll
        for (int t = 0; t < 2; t++) {
            const int row = tid >> 3, dcp = tid & 7;
            const int d0 = (dcp ^ (row & 7)) * 8;
            const ushort* qg = qkv + (tok0 + bases[t] + row) * (3 * D_) + h * DH_ + d0;
            async_copy16(qg, lds + 32768 + t * 16384 + tid * 16);
        }
    }
    __syncthreads();
    bf16x8 aq[2];
    #pragma unroll
    for (int ks = 0; ks < 2; ks++) {
        const int row = wq * 16 + r16;
        aq[ks] = *(const bf16x8*)(lds + pq + row * 128 + ((ks * 64 + kc * 16) ^ rx));
    }

    f32x4 o[4];
    float m[4], l[4], corr[4];
    #pragma unroll
    for (int nd = 0; nd < 4; nd++) { f32x4 z = {0.f, 0.f, 0.f, 0.f}; o[nd] = z; }
    #pragma unroll
    for (int j = 0; j < 4; j++) { m[j] = -1e30f; l[j] = 0.f; }

    const int nchunks = (17 - ip) >> 1;
    for (int ch = 0; ch < nchunks; ch++) {
        const int kb = ch << 7;
        __syncthreads();
        #pragma unroll
        for (int i = 0; i < 2; i++) {
            const int slot = i * 512 + tid;
            const int row = slot >> 3, dcp = slot & 7;
            const int d0 = (dcp ^ (row & 7)) * 8;
            async_copy16(kg + (size_t)(kb + row) * (3 * D_) + d0, lds + slot * 16);
        }
        {
            const int key = tid >> 2, dbase = (tid & 3) * 16;
            const ushort* src = vg + (size_t)(kb + key) * (3 * D_) + dbase;
            bf16x8 v0 = *(const bf16x8*)(src);
            bf16x8 v1 = *(const bf16x8*)(src + 8);
            #pragma unroll
            for (int e = 0; e < 8; e++) {
                int d = dbase + e;
                *(ushort*)(lds + 16384 + d * 256 + ((key * 2) ^ ((d & 7) << 4))) = (ushort)v0[e];
                d = dbase + 8 + e;
                *(ushort*)(lds + 16384 + d * 256 + ((key * 2) ^ ((d & 7) << 4))) = (ushort)v1[e];
            }
        }
        __syncthreads();

        const bool active = (tw == 0) || (kb < lob + 64);
        if (active) {
            f32x4 s[8];
            #pragma unroll
            for (int ni = 0; ni < 8; ni++) { f32x4 z = {0.f, 0.f, 0.f, 0.f}; s[ni] = z; }
            __builtin_amdgcn_s_setprio(1);
            #pragma unroll
            for (int ks = 0; ks < 2; ks++)
                #pragma unroll
                for (int ni = 0; ni < 8; ni++) {
                    const int row = ni * 16 + r16;
                    bf16x8 kf = *(const bf16x8*)(lds + row * 128 + ((ks * 64 + kc * 16) ^ rx));
                    s[ni] = __builtin_amdgcn_mfma_f32_16x16x32_bf16(aq[ks], kf, s[ni], 0, 0, 0);
                }
            __builtin_amdgcn_s_setprio(0);

            const bool needmask = (kb + 127 > tb);
            #pragma unroll
            for (int j = 0; j < 4; j++) {
                const int qrow = tb + wq * 16 + kc * 4 + j;
                #pragma unroll
                for (int ni = 0; ni < 8; ni++) {
                    float v = s[ni][j] * SCALE_LOG2E;
                    if (needmask) { int key = kb + ni * 16 + r16; if (key > qrow) v = -1e30f; }
                    s[ni][j] = v;
                }
                float t0 = fmaxf(fmaxf(s[0][j], s[1][j]), fmaxf(s[2][j], s[3][j]));
                float t1 = fmaxf(fmaxf(s[4][j], s[5][j]), fmaxf(s[6][j], s[7][j]));
                float tmax = fmaxf(t0, t1);
                #pragma unroll
                for (int off = 1; off < 16; off <<= 1) tmax = fmaxf(tmax, __shfl_xor(tmax, off));
                const float mn = fmaxf(m[j], tmax);
                corr[j] = exp2f(m[j] - mn);
                m[j] = mn;
                float ps = 0.f;
                #pragma unroll
                for (int ni = 0; ni < 8; ni++) {
                    float p = exp2f(s[ni][j] - mn);
                    s[ni][j] = p;
                    ps += p;
                }
                #pragma unroll
                for (int off = 1; off < 16; off <<= 1) ps += __shfl_xor(ps, off);
                l[j] = l[j] * corr[j] + ps;
            }
            #pragma unroll
            for (int ni = 0; ni < 8; ni++)
                #pragma unroll
                for (int j = 0; j < 4; j++) {
                    const int row = wq * 16 + kc * 4 + j;
                    *(ushort*)(lds + pq + row * 256 + ((ni * 32 + r16 * 2) ^ ((row & 7) << 4))) = f2bf(s[ni][j]);
                }
            #pragma unroll
            for (int nd = 0; nd < 4; nd++)
                #pragma unroll
                for (int j = 0; j < 4; j++) o[nd][j] *= corr[j];
            __builtin_amdgcn_s_setprio(1);
            #pragma unroll
            for (int ks = 0; ks < 4; ks++) {
                const int prow = wq * 16 + r16;
                bf16x8 pf = *(const bf16x8*)(lds + pq + prow * 256 + ((ks * 64 + kc * 16) ^ rx));
                #pragma unroll
                for (int nd = 0; nd < 4; nd++) {
                    const int drow = nd * 16 + r16;
                    bf16x8 vf = *(const bf16x8*)(lds + 16384 + drow * 256 + ((ks * 64 + kc * 16) ^ rx));
                    o[nd] = __builtin_amdgcn_mfma_f32_16x16x32_bf16(pf, vf, o[nd], 0, 0, 0);
                }
            }
            __builtin_amdgcn_s_setprio(0);
        }
    }

    #pragma unroll
    for (int j = 0; j < 4; j++) {
        const float inv = 1.0f / l[j];
        const int row = tb + wq * 16 + kc * 4 + j;
        ushort* dst = ctx + (tok0 + row) * D_ + h * DH_;
        #pragma unroll
        for (int nd = 0; nd < 4; nd++)
            dst[nd * 16 + r16] = f2bf(o[nd][j] * inv);
    }
}

extern "C" void kernel_launch(void* const* d_in, const int* in_sizes, int n_in,
                              void* d_out, int out_size, void* d_ws, size_t ws_size,
                              hipStream_t stream) {
    const int*   xi   = (const int*)d_in[0];
    const float* emb  = (const float*)d_in[1];
    const float* Wqkv = (const float*)d_in[2];
    const float* Wout = (const float*)d_in[3];
    const float* W1   = (const float*)d_in[4];
    const float* W2   = (const float*)d_in[5];
    const float* lmh  = (const float*)d_in[6];
    float* out = (float*)d_out;

    const size_t NT = (size_t)B_ * T_;
    size_t off = 0;
    auto carve = [&](size_t bytes) -> char* {
        char* r = (char*)d_ws + off;
        off += (bytes + 255) & ~(size_t)255;
        return r;
    };
    float*  xbuf = (float*)carve(NT * D_ * 4);
    ushort* qkv  = (ushort*)carve(NT * 3 * D_ * 2);
    ushort* nb   = (ushort*)carve(NT * D_ * 2);
    ushort* ctxb = (ushort*)carve(NT * D_ * 2);
    ushort* hb   = (ushort*)carve(NT * 4 * D_ * 2);
    float*  cosT = (float*)carve(T_ * 32 * 4);
    float*  sinT = (float*)carve(T_ * 32 * 4);

    const size_t nWqkv = (size_t)L_ * 3 * D_ * D_;
    const size_t nWout = (size_t)L_ * D_ * D_;
    const size_t nW1   = (size_t)L_ * 4 * D_ * D_;
    const size_t nW2   = (size_t)L_ * 4 * D_ * D_;
    const size_t nLmh  = (size_t)V_ * D_;
    ushort* WqkvB = (ushort*)carve(nWqkv * 2);
    ushort* WoutB = (ushort*)carve(nWout * 2);
    ushort* W1B   = (ushort*)carve(nW1 * 2);
    ushort* W2B   = (ushort*)carve(nW2 * 2);
    ushort* lmhB  = (ushort*)carve(nLmh * 2);
    const bool preconv = (off <= ws_size);

    if (preconv) {
        k_cast<<<dim3(2048), dim3(256), 0, stream>>>((const float4*)Wqkv, (ushort4*)WqkvB, (int)(nWqkv / 4));
        k_cast<<<dim3(2048), dim3(256), 0, stream>>>((const float4*)Wout, (ushort4*)WoutB, (int)(nWout / 4));
        k_cast<<<dim3(2048), dim3(256), 0, stream>>>((const float4*)W1,   (ushort4*)W1B,   (int)(nW1 / 4));
        k_cast<<<dim3(2048), dim3(256), 0, stream>>>((const float4*)W2,   (ushort4*)W2B,   (int)(nW2 / 4));
        k_cast<<<dim3(2048), dim3(256), 0, stream>>>((const float4*)lmh,  (ushort4*)lmhB,  (int)(nLmh / 4));
    }

#define LAUNCH_GEMM(BN, EPI, OUTBF, SPLITK, GX, GY, GZ, Aq, Wb16, Wf32, Cq, Rq, Mv, Nv, Kv)  \
    do {                                                                                     \
        if (preconv)                                                                         \
            k_mfma_gemm<BN, EPI, OUTBF, false, SPLITK><<<dim3(GX, GY, GZ), dim3(256), 0, stream>>>( \
                (const ushort*)(Aq), (const void*)(Wb16), (void*)(Cq), (Rq), cosT, sinT,     \
                Mv, Nv, Kv);                                                                 \
        else                                                                                 \
            k_mfma_gemm<BN, EPI, OUTBF, true, SPLITK><<<dim3(GX, GY, GZ), dim3(256), 0, stream>>>( \
                (const ushort*)(Aq), (const void*)(Wf32), (void*)(Cq), (Rq), cosT, sinT,     \
                Mv, Nv, Kv);                                                                 \
    } while (0)

    k_rope_tables<<<dim3(T_), dim3(32), 0, stream>>>(cosT, sinT);
    k_gather<<<dim3(NT), dim3(256), 0, stream>>>(xi, emb, xbuf);

    for (int l = 0; l < L_; l++) {
        k_rmsnorm<<<dim3(NT), dim3(256), 0, stream>>>(xbuf, nb);
        // qkv = rope(n * Wqkv^T), bf16
        LAUNCH_GEMM(128, 3, true, false, 16, 24, 1, nb,
                    WqkvB + (size_t)l * 3 * D_ * D_, Wqkv + (size_t)l * 3 * D_ * D_,
                    qkv, nullptr, (int)NT, 3 * D_, D_);
        k_attn_p8<<<dim3(8, B_ * H_), dim3(512), 0, stream>>>(qkv, ctxb);
        // x += ctx * Wout^T  (split-K=2, atomicAdd into xbuf)
        LAUNCH_GEMM(64, 4, false, true, 16, 16, 2, ctxb,
                    WoutB + (size_t)l * D_ * D_, Wout + (size_t)l * D_ * D_,
                    xbuf, nullptr, (int)NT, D_, D_);
        k_rmsnorm<<<dim3(NT), dim3(256), 0, stream>>>(xbuf, nb);
        // h = relu(n * W1^T)^2, bf16  (BN=256 high-intensity tile)
        LAUNCH_GEMM(256, 2, true, false, 16, 16, 1, nb,
                    W1B + (size_t)l * 4 * D_ * D_, W1 + (size_t)l * 4 * D_ * D_,
                    hb, nullptr, (int)NT, 4 * D_, D_);
        // x += h * W2^T  (split-K=2, atomicAdd into xbuf)
        LAUNCH_GEMM(64, 4, false, true, 16, 16, 2, hb,
                    W2B + (size_t)l * 4 * D_ * D_, W2 + (size_t)l * 4 * D_ * D_,
                    xbuf, nullptr, (int)NT, D_, 4 * D_);
    }
    k_rmsnorm<<<dim3(NT), dim3(256), 0, stream>>>(xbuf, nb);
    LAUNCH_GEMM(256, 0, false, false, 16, 125, 1, nb, lmhB, lmh, out, nullptr, (int)NT, V_, D_);
#undef LAUNCH_GEMM
}

// Round 16
// 1734.509 us; speedup vs baseline: 1.1289x; 1.0067x over previous
//
#include <hip/hip_runtime.h>
#include <hip/hip_bf16.h>
#include <cmath>
#include <cstdint>

#define B_  2
#define T_  1024
#define V_  32000
#define D_  1024
#define H_  16
#define L_  8
#define DH_ 64

typedef __attribute__((ext_vector_type(8))) short bf16x8;
typedef __attribute__((ext_vector_type(4))) float f32x4;

__device__ __forceinline__ ushort f2bf(float f) {
    union { float f; uint32_t u; } v; v.f = f;
    uint32_t r = v.u + 0x7FFFu + ((v.u >> 16) & 1u);
    return (ushort)(r >> 16);
}
__device__ __forceinline__ float bf2f(ushort u) {
    union { uint32_t u; float f; } v; v.u = ((uint32_t)u) << 16;
    return v.f;
}

__device__ __forceinline__ void async_copy16(const void* g, void* l) {
    __builtin_amdgcn_global_load_lds(
        (const __attribute__((address_space(1))) void*)g,
        (__attribute__((address_space(3))) void*)l, 16, 0, 0);
}

// ---------------- fp32 -> bf16 cast (weights) ----------------
__global__ __launch_bounds__(256) void k_cast(const float4* __restrict__ in,
                                              ushort4* __restrict__ out, int n4) {
    for (int i = blockIdx.x * 256 + threadIdx.x; i < n4; i += gridDim.x * 256) {
        float4 v = in[i];
        out[i] = make_ushort4(f2bf(v.x), f2bf(v.y), f2bf(v.z), f2bf(v.w));
    }
}

// ---------------- RoPE tables: cos/sin (T, 32) ----------------
__global__ void k_rope_tables(float* __restrict__ cosT, float* __restrict__ sinT) {
    int t = blockIdx.x;
    int i = threadIdx.x;           // 0..31
    float invf = (i < 16) ? powf(1000.0f, -(float)i / 16.0f) : 0.0f;
    float th = (float)t * invf;
    cosT[t * 32 + i] = cosf(th);
    sinT[t * 32 + i] = sinf(th);
}

// ---------------- Embedding gather (fp32 x) ----------------
__global__ __launch_bounds__(256) void k_gather(const int* __restrict__ idx,
                                                const float* __restrict__ emb,
                                                float* __restrict__ x) {
    int row = blockIdx.x;
    int id = idx[row];
    const float4* src = (const float4*)(emb + (size_t)id * D_);
    float4* dst = (float4*)(x + (size_t)row * D_);
    dst[threadIdx.x] = src[threadIdx.x];
}

// ---------------- RMSNorm: bf16 out ----------------
__global__ __launch_bounds__(256) void k_rmsnorm(const float* __restrict__ x,
                                                 ushort* __restrict__ out) {
    int row = blockIdx.x;
    const float4* xr = (const float4*)(x + (size_t)row * D_);
    float4 v = xr[threadIdx.x];
    float ss = v.x * v.x + v.y * v.y + v.z * v.z + v.w * v.w;
    #pragma unroll
    for (int off = 1; off < 64; off <<= 1) ss += __shfl_xor(ss, off);
    __shared__ float wsum[4];
    int lane = threadIdx.x & 63, wv = threadIdx.x >> 6;
    if (lane == 0) wsum[wv] = ss;
    __syncthreads();
    float tot = wsum[0] + wsum[1] + wsum[2] + wsum[3];
    float inv = rsqrtf(tot * (1.0f / D_) + 1e-6f);
    ushort4 r = make_ushort4(f2bf(v.x * inv), f2bf(v.y * inv), f2bf(v.z * inv), f2bf(v.w * inv));
    *(ushort4*)(out + (size_t)row * D_ + threadIdx.x * 4) = r;
}

// ---------------- MFMA GEMM: BM=128, BK=64, T2 swizzle, T1 swizzle ----------------
// BN<=128: prefetch double-buffer. BN=256: single buffer, high-intensity tile.
// EPI: 0 none(+nontemporal), 1 +Res(fp32), 2 relu^2, 3 RoPE(qkv), 4 atomicAdd(fp32).
// SPLITK: gridDim.z blocks each accumulate K/gridDim.z (use with EPI=4).
template<int BN, int EPI, bool OUTBF, bool CONVB, bool SPLITK>
__global__ __launch_bounds__(256, 2) void k_mfma_gemm(const ushort* __restrict__ A,
                                                      const void* __restrict__ Wp,
                                                      void* __restrict__ Cp,
                                                      const float* __restrict__ Res,
                                                      const float* __restrict__ cosT,
                                                      const float* __restrict__ sinT,
                                                      int M, int N, int K) {
    constexpr int BM = 128;
    constexpr int MI = 4;
    constexpr int NI = BN / 32;
    constexpr bool DBUF = (BN <= 128);
    constexpr int NB = DBUF ? 2 : 1;
    __shared__ ushort As[NB][BM][64];
    __shared__ ushort Bs[NB][BN][64];
    const int tid = threadIdx.x;
    const int wid = tid >> 6, lane = tid & 63;
    const int wr = wid >> 1, wc = wid & 1;
    const int r16 = lane & 15, kc = lane >> 4;
    const int rx = (r16 & 7) << 4;
    const int srow8 = tid >> 3;
    const int sdcp = tid & 7;

    const int nwg = gridDim.x * gridDim.y;
    int orig = blockIdx.y * gridDim.x + blockIdx.x;
    int swz = (nwg & 7) ? orig : ((orig & 7) * (nwg >> 3) + (orig >> 3));
    const size_t bm = (size_t)(swz % gridDim.x) * BM;
    const size_t bn = (size_t)(swz / gridDim.x) * BN;

    const int KSTEPS = SPLITK ? (K >> 7) : (K >> 6);
    const int kbase  = SPLITK ? (int)blockIdx.z * (K >> 1) : 0;

    auto stage = [&](int buf, int k0) {
        #pragma unroll
        for (int i = 0; i < 4; i++) {
            const int row = i * 32 + srow8;
            const ushort* g = A + (bm + row) * (size_t)K + k0 + ((sdcp ^ (row & 7)) * 8);
            async_copy16(g, (char*)As + buf * (BM * 128) + (i * 256 + tid) * 16);
        }
        if constexpr (!CONVB) {
            const ushort* Wb = (const ushort*)Wp;
            #pragma unroll
            for (int i = 0; i < BN / 32; i++) {
                const int row = i * 32 + srow8;
                const ushort* g = Wb + (bn + row) * (size_t)K + k0 + ((sdcp ^ (row & 7)) * 8);
                async_copy16(g, (char*)Bs + buf * (BN * 128) + (i * 256 + tid) * 16);
            }
        } else {
            const float* Wf = (const float*)Wp;
            #pragma unroll
            for (int i = 0; i < BN / 32; i++) {
                const int row = i * 32 + srow8;
                const float* src = Wf + (bn + row) * (size_t)K + k0 + sdcp * 8;
                float4 v0 = *(const float4*)(src);
                float4 v1 = *(const float4*)(src + 4);
                union { ushort u[8]; bf16x8 v; } tmp;
                tmp.u[0] = f2bf(v0.x); tmp.u[1] = f2bf(v0.y);
                tmp.u[2] = f2bf(v0.z); tmp.u[3] = f2bf(v0.w);
                tmp.u[4] = f2bf(v1.x); tmp.u[5] = f2bf(v1.y);
                tmp.u[6] = f2bf(v1.z); tmp.u[7] = f2bf(v1.w);
                *(bf16x8*)((char*)Bs + buf * (BN * 128) + row * 128 + ((sdcp ^ (row & 7)) << 4)) = tmp.v;
            }
        }
    };

    f32x4 acc[MI][NI];
    #pragma unroll
    for (int mi = 0; mi < MI; mi++)
        #pragma unroll
        for (int ni = 0; ni < NI; ni++) {
            f32x4 z = {0.f, 0.f, 0.f, 0.f};
            acc[mi][ni] = z;
        }

    auto compute = [&](int buf) {
        #pragma unroll
        for (int kk = 0; kk < 2; kk++) {
            bf16x8 af[MI], bfr[NI];
            #pragma unroll
            for (int mi = 0; mi < MI; mi++)
                af[mi] = *(const bf16x8*)((const char*)As + buf * (BM * 128) +
                                          (wr * 64 + mi * 16 + r16) * 128 +
                                          ((kk * 64 + kc * 16) ^ rx));
            #pragma unroll
            for (int ni = 0; ni < NI; ni++)
                bfr[ni] = *(const bf16x8*)((const char*)Bs + buf * (BN * 128) +
                                           (wc * (BN / 2) + ni * 16 + r16) * 128 +
                                           ((kk * 64 + kc * 16) ^ rx));
            #pragma unroll
            for (int mi = 0; mi < MI; mi++)
                #pragma unroll
                for (int ni = 0; ni < NI; ni++)
                    acc[mi][ni] = __builtin_amdgcn_mfma_f32_16x16x32_bf16(af[mi], bfr[ni],
                                                                          acc[mi][ni], 0, 0, 0);
        }
    };

    if constexpr (DBUF) {
        stage(0, kbase);
        __syncthreads();
        for (int step = 0; step < KSTEPS; ++step) {
            const int cur = step & 1;
            if (step + 1 < KSTEPS) stage(cur ^ 1, kbase + ((step + 1) << 6));
            compute(cur);
            __syncthreads();
        }
    } else {
        for (int step = 0; step < KSTEPS; ++step) {
            stage(0, kbase + (step << 6));
            __syncthreads();
            compute(0);
            __syncthreads();
        }
    }

    #pragma unroll
    for (int mi = 0; mi < MI; mi++) {
        #pragma unroll
        for (int j = 0; j < 4; j++) {
            const size_t row = bm + wr * 64 + mi * 16 + (lane >> 4) * 4 + j;
            if constexpr (EPI == 3) {
                static_assert(BN == 128, "rope epilogue assumes BN=128");
                const int sec = (int)((bn + wc * 64) >> 10);   // 0=q,1=k,2=v
                if (sec < 2) {
                    const int t = (int)(row & (T_ - 1));
                    #pragma unroll
                    for (int np = 0; np < 2; np++) {
                        const int i1 = np * 16 + r16;          // 0..31
                        float c = cosT[t * 32 + i1], s = sinT[t * 32 + i1];
                        float x1 = acc[mi][np][j], x2 = acc[mi][np + 2][j];
                        acc[mi][np][j]     = c * x1 - s * x2;
                        acc[mi][np + 2][j] = s * x1 + c * x2;
                    }
                }
            }
            #pragma unroll
            for (int ni = 0; ni < NI; ni++) {
                const size_t col = bn + wc * (BN / 2) + ni * 16 + r16;
                float v = acc[mi][ni][j];
                if constexpr (EPI == 1) v += Res[row * N + col];
                if constexpr (EPI == 2) { v = fmaxf(v, 0.f); v *= v; }
                if constexpr (EPI == 4) {
                    atomicAdd((float*)Cp + row * N + col, v);
                } else if constexpr (OUTBF) {
                    ((ushort*)Cp)[row * N + col] = f2bf(v);
                } else if constexpr (EPI == 0) {
                    __builtin_nontemporal_store(v, (float*)Cp + row * N + col);
                } else {
                    ((float*)Cp)[row * N + col] = v;
                }
            }
        }
    }
}

// ---------------- 256x256 8-wave GEMM with half-tile counted-vmcnt pipeline ----------------
// LDS per buffer: 4 parts x 16KB. PA0 = A rows {0-63,128-191}, PA1 = complement (bit6 split);
// PB0 = B rows with (row&32)==0, PB1 = complement (bit5 split). Part = 2 loads/thread.
// Phases (mh,nh): (0,0)->(0,1)->(1,1)->(1,0); issue order A0,B0,B1,A1 matches consumption.
// Waits: vmcnt(4)/(4)/(4)/none steady-state (>=4 loads always in flight); last tile 4/2/0.
__global__ __launch_bounds__(512, 2) void k_gemm256c(const ushort* __restrict__ A,
                                                     const ushort* __restrict__ Wb,
                                                     float* __restrict__ C,
                                                     int M, int N, int K) {
    __shared__ __align__(16) char lds[131072];   // [buf 64KB][part 16KB][srow7*128 + swz-chunk]
    const int tid = threadIdx.x;
    const int wid = tid >> 6, lane = tid & 63;
    const int wr = wid >> 2, wc = wid & 3;       // 2 x 4 wave grid
    const int r16 = lane & 15, kc = lane >> 4;
    const int rx = (r16 & 7) << 4;

    const int nwg = gridDim.x * gridDim.y;
    int orig = blockIdx.y * gridDim.x + blockIdx.x;
    int swz = (nwg & 7) ? orig : ((orig & 7) * (nwg >> 3) + (orig >> 3));
    const size_t bm = (size_t)(swz % gridDim.x) * 256;
    const size_t bn = (size_t)(swz / gridDim.x) * 256;

    // part: 0=PA0, 1=PA1, 2=PB0, 3=PB1
    auto stagep = [&](int buf, int part, int k0) {
        #pragma unroll
        for (int i = 0; i < 2; i++) {
            const int s = i * 512 + tid;
            const int sr = s >> 3, ch = s & 7;
            const int gcol = (ch ^ (sr & 7)) * 8;
            int grow;
            const ushort* base;
            if (part < 2) {
                grow = (sr >> 6) * 128 + part * 64 + (sr & 63);
                base = A + (bm + grow) * (size_t)K;
            } else {
                grow = (sr >> 5) * 64 + (part - 2) * 32 + (sr & 31);
                base = Wb + (bn + grow) * (size_t)K;
            }
            async_copy16(base + k0 + gcol, lds + buf * 65536 + part * 16384 + s * 16);
        }
    };

    f32x4 acc[8][4];
    #pragma unroll
    for (int mi = 0; mi < 8; mi++)
        #pragma unroll
        for (int ni = 0; ni < 4; ni++) {
            f32x4 z = {0.f, 0.f, 0.f, 0.f};
            acc[mi][ni] = z;
        }

    bf16x8 af[4][2], bfA[2][2], bfB[2][2];
    auto loadA_ = [&](int buf, int mh) {
        #pragma unroll
        for (int q = 0; q < 4; q++)
            #pragma unroll
            for (int kk = 0; kk < 2; kk++)
                af[q][kk] = *(const bf16x8*)(lds + buf * 65536 + mh * 16384 +
                                             (wr * 64 + q * 16 + r16) * 128 +
                                             ((kk * 64 + kc * 16) ^ rx));
    };
    auto loadB_ = [&](int buf, int nh, bf16x8 (&bf)[2][2]) {
        #pragma unroll
        for (int r = 0; r < 2; r++)
            #pragma unroll
            for (int kk = 0; kk < 2; kk++)
                bf[r][kk] = *(const bf16x8*)(lds + buf * 65536 + 32768 + nh * 16384 +
                                             (wc * 32 + r * 16 + r16) * 128 +
                                             ((kk * 64 + kc * 16) ^ rx));
    };
    auto quad = [&](int mh, int nh, bf16x8 (&bf)[2][2]) {
        __builtin_amdgcn_s_setprio(1);
        #pragma unroll
        for (int kk = 0; kk < 2; kk++)
            #pragma unroll
            for (int q = 0; q < 4; q++)
                #pragma unroll
                for (int r = 0; r < 2; r++)
                    acc[mh * 4 + q][nh * 2 + r] =
                        __builtin_amdgcn_mfma_f32_16x16x32_bf16(af[q][kk], bf[r][kk],
                                                                acc[mh * 4 + q][nh * 2 + r], 0, 0, 0);
        __builtin_amdgcn_s_setprio(0);
    };

    const int KS = K >> 6;   // 16
    // prologue: tile 0, issue order A0, B0, B1, A1
    stagep(0, 0, 0); stagep(0, 2, 0); stagep(0, 3, 0); stagep(0, 1, 0);

    for (int t = 0; t < KS; ++t) {
        const int cur = t & 1, nxt = cur ^ 1;
        const bool pre = (t + 1 < KS);
        const int k1 = (t + 1) << 6;
        // phase 0: (mh0, nh0) — needs PA0, PB0 of cur
        asm volatile("s_waitcnt vmcnt(4)" ::: "memory");
        asm volatile("s_barrier" ::: "memory");
        if (pre) stagep(nxt, 0, k1);
        loadA_(cur, 0); loadB_(cur, 0, bfA);
        quad(0, 0, bfA);
        // phase 1: (mh0, nh1) — needs PB1
        if (pre) asm volatile("s_waitcnt vmcnt(4)" ::: "memory");
        else     asm volatile("s_waitcnt vmcnt(2)" ::: "memory");
        asm volatile("s_barrier" ::: "memory");
        if (pre) stagep(nxt, 2, k1);
        loadB_(cur, 1, bfB);
        quad(0, 1, bfB);
        // phase 2: (mh1, nh1) — needs PA1
        if (pre) asm volatile("s_waitcnt vmcnt(4)" ::: "memory");
        else     asm volatile("s_waitcnt vmcnt(0)" ::: "memory");
        asm volatile("s_barrier" ::: "memory");
        if (pre) stagep(nxt, 3, k1);
        loadA_(cur, 1);
        quad(1, 1, bfB);
        // phase 3: (mh1, nh0) — regs only
        if (pre) stagep(nxt, 1, k1);
        quad(1, 0, bfA);
    }

    // epilogue: row = bm + wr*128 + mi*16 + (lane>>4)*4 + j ; col = bn + wc*64 + ni*16 + r16
    #pragma unroll
    for (int mi = 0; mi < 8; mi++) {
        #pragma unroll
        for (int j = 0; j < 4; j++) {
            const size_t row = bm + wr * 128 + mi * 16 + (lane >> 4) * 4 + j;
            #pragma unroll
            for (int ni = 0; ni < 4; ni++) {
                const size_t col = bn + wc * 64 + ni * 16 + r16;
                __builtin_nontemporal_store(acc[mi][ni][j], C + row * (size_t)N + col);
            }
        }
    }
}

// ---------------- 8-wave paired flash attention, KVBLK=128 (R13, best) ----------------
__global__ __launch_bounds__(512) void k_attn_p8(const ushort* __restrict__ qkv,
                                                 ushort* __restrict__ ctx) {
    __shared__ __align__(16) char lds[65536];
    const int tid = threadIdx.x;
    const int w = tid >> 6, lane = tid & 63;
    const int r16 = lane & 15, kc = lane >> 4;
    const int rx = (r16 & 7) << 4;
    const int ip = blockIdx.x;                 // 0..7
    const int tw = w >> 2;                     // 0 = hi tile, 1 = lo tile
    const int wq = w & 3;
    const int hib = (15 - ip) * 64, lob = ip * 64;
    const int tb = tw ? lob : hib;
    const int pq = 32768 + tw * 16384;
    const int bh = blockIdx.y, b = bh >> 4, h = bh & 15;
    const size_t tok0 = (size_t)b * T_;
    const ushort* kg = qkv + tok0 * (3 * D_) + D_ + h * DH_;
    const ushort* vg = qkv + tok0 * (3 * D_) + 2 * D_ + h * DH_;
    const float SCALE_LOG2E = 0.125f * 1.44269504089f;

    {
        const int bases[2] = { hib, lob };
        #pragma unroll
        for (int t = 0; t < 2; t++) {
            const int row = tid >> 3, dcp = tid & 7;
            const int d0 = (dcp ^ (row & 7)) * 8;
            const ushort* qg = qkv + (tok0 + bases[t] + row) * (3 * D_) + h * DH_ + d0;
            async_copy16(qg, lds + 32768 + t * 16384 + tid * 16);
        }
    }
    __syncthreads();
    bf16x8 aq[2];
    #pragma unroll
    for (int ks = 0; ks < 2; ks++) {
        const int row = wq * 16 + r16;
        aq[ks] = *(const bf16x8*)(lds + pq + row * 128 + ((ks * 64 + kc * 16) ^ rx));
    }

    f32x4 o[4];
    float m[4], l[4], corr[4];
    #pragma unroll
    for (int nd = 0; nd < 4; nd++) { f32x4 z = {0.f, 0.f, 0.f, 0.f}; o[nd] = z; }
    #pragma unroll
    for (int j = 0; j < 4; j++) { m[j] = -1e30f; l[j] = 0.f; }

    const int nchunks = (17 - ip) >> 1;
    for (int ch = 0; ch < nchunks; ch++) {
        const int kb = ch << 7;
        __syncthreads();
        #pragma unroll
        for (int i = 0; i < 2; i++) {
            const int slot = i * 512 + tid;
            const int row = slot >> 3, dcp = slot & 7;
            const int d0 = (dcp ^ (row & 7)) * 8;
            async_copy16(kg + (size_t)(kb + row) * (3 * D_) + d0, lds + slot * 16);
        }
        {
            const int key = tid >> 2, dbase = (tid & 3) * 16;
            const ushort* src = vg + (size_t)(kb + key) * (3 * D_) + dbase;
            bf16x8 v0 = *(const bf16x8*)(src);
            bf16x8 v1 = *(const bf16x8*)(src + 8);
            #pragma unroll
            for (int e = 0; e < 8; e++) {
                int d = dbase + e;
                *(ushort*)(lds + 16384 + d * 256 + ((key * 2) ^ ((d & 7) << 4))) = (ushort)v0[e];
                d = dbase + 8 + e;
                *(ushort*)(lds + 16384 + d * 256 + ((key * 2) ^ ((d & 7) << 4))) = (ushort)v1[e];
            }
        }
        __syncthreads();

        const bool active = (tw == 0) || (kb < lob + 64);
        if (active) {
            f32x4 s[8];
            #pragma unroll
            for (int ni = 0; ni < 8; ni++) { f32x4 z = {0.f, 0.f, 0.f, 0.f}; s[ni] = z; }
            __builtin_amdgcn_s_setprio(1);
            #pragma unroll
            for (int ks = 0; ks < 2; ks++)
                #pragma unroll
                for (int ni = 0; ni < 8; ni++) {
                    const int row = ni * 16 + r16;
                    bf16x8 kf = *(const bf16x8*)(lds + row * 128 + ((ks * 64 + kc * 16) ^ rx));
                    s[ni] = __builtin_amdgcn_mfma_f32_16x16x32_bf16(aq[ks], kf, s[ni], 0, 0, 0);
                }
            __builtin_amdgcn_s_setprio(0);

            const bool needmask = (kb + 127 > tb);
            #pragma unroll
            for (int j = 0; j < 4; j++) {
                const int qrow = tb + wq * 16 + kc * 4 + j;
                #pragma unroll
                for (int ni = 0; ni < 8; ni++) {
                    float v = s[ni][j] * SCALE_LOG2E;
                    if (needmask) { int key = kb + ni * 16 + r16; if (key > qrow) v = -1e30f; }
                    s[ni][j] = v;
                }
                float t0 = fmaxf(fmaxf(s[0][j], s[1][j]), fmaxf(s[2][j], s[3][j]));
                float t1 = fmaxf(fmaxf(s[4][j], s[5][j]), fmaxf(s[6][j], s[7][j]));
                float tmax = fmaxf(t0, t1);
                #pragma unroll
                for (int off = 1; off < 16; off <<= 1) tmax = fmaxf(tmax, __shfl_xor(tmax, off));
                const float mn = fmaxf(m[j], tmax);
                corr[j] = exp2f(m[j] - mn);
                m[j] = mn;
                float ps = 0.f;
                #pragma unroll
                for (int ni = 0; ni < 8; ni++) {
                    float p = exp2f(s[ni][j] - mn);
                    s[ni][j] = p;
                    ps += p;
                }
                #pragma unroll
                for (int off = 1; off < 16; off <<= 1) ps += __shfl_xor(ps, off);
                l[j] = l[j] * corr[j] + ps;
            }
            #pragma unroll
            for (int ni = 0; ni < 8; ni++)
                #pragma unroll
                for (int j = 0; j < 4; j++) {
                    const int row = wq * 16 + kc * 4 + j;
                    *(ushort*)(lds + pq + row * 256 + ((ni * 32 + r16 * 2) ^ ((row & 7) << 4))) = f2bf(s[ni][j]);
                }
            #pragma unroll
            for (int nd = 0; nd < 4; nd++)
                #pragma unroll
                for (int j = 0; j < 4; j++) o[nd][j] *= corr[j];
            __builtin_amdgcn_s_setprio(1);
            #pragma unroll
            for (int ks = 0; ks < 4; ks++) {
                const int prow = wq * 16 + r16;
                bf16x8 pf = *(const bf16x8*)(lds + pq + prow * 256 + ((ks * 64 + kc * 16) ^ rx));
                #pragma unroll
                for (int nd = 0; nd < 4; nd++) {
                    const int drow = nd * 16 + r16;
                    bf16x8 vf = *(const bf16x8*)(lds + 16384 + drow * 256 + ((ks * 64 + kc * 16) ^ rx));
                    o[nd] = __builtin_amdgcn_mfma_f32_16x16x32_bf16(pf, vf, o[nd], 0, 0, 0);
                }
            }
            __builtin_amdgcn_s_setprio(0);
        }
    }

    #pragma unroll
    for (int j = 0; j < 4; j++) {
        const float inv = 1.0f / l[j];
        const int row = tb + wq * 16 + kc * 4 + j;
        ushort* dst = ctx + (tok0 + row) * D_ + h * DH_;
        #pragma unroll
        for (int nd = 0; nd < 4; nd++)
            dst[nd * 16 + r16] = f2bf(o[nd][j] * inv);
    }
}

extern "C" void kernel_launch(void* const* d_in, const int* in_sizes, int n_in,
                              void* d_out, int out_size, void* d_ws, size_t ws_size,
                              hipStream_t stream) {
    const int*   xi   = (const int*)d_in[0];
    const float* emb  = (const float*)d_in[1];
    const float* Wqkv = (const float*)d_in[2];
    const float* Wout = (const float*)d_in[3];
    const float* W1   = (const float*)d_in[4];
    const float* W2   = (const float*)d_in[5];
    const float* lmh  = (const float*)d_in[6];
    float* out = (float*)d_out;

    const size_t NT = (size_t)B_ * T_;
    size_t off = 0;
    auto carve = [&](size_t bytes) -> char* {
        char* r = (char*)d_ws + off;
        off += (bytes + 255) & ~(size_t)255;
        return r;
    };
    float*  xbuf = (float*)carve(NT * D_ * 4);
    ushort* qkv  = (ushort*)carve(NT * 3 * D_ * 2);
    ushort* nb   = (ushort*)carve(NT * D_ * 2);
    ushort* ctxb = (ushort*)carve(NT * D_ * 2);
    ushort* hb   = (ushort*)carve(NT * 4 * D_ * 2);
    float*  cosT = (float*)carve(T_ * 32 * 4);
    float*  sinT = (float*)carve(T_ * 32 * 4);

    const size_t nWqkv = (size_t)L_ * 3 * D_ * D_;
    const size_t nWout = (size_t)L_ * D_ * D_;
    const size_t nW1   = (size_t)L_ * 4 * D_ * D_;
    const size_t nW2   = (size_t)L_ * 4 * D_ * D_;
    const size_t nLmh  = (size_t)V_ * D_;
    ushort* WqkvB = (ushort*)carve(nWqkv * 2);
    ushort* WoutB = (ushort*)carve(nWout * 2);
    ushort* W1B   = (ushort*)carve(nW1 * 2);
    ushort* W2B   = (ushort*)carve(nW2 * 2);
    ushort* lmhB  = (ushort*)carve(nLmh * 2);
    const bool preconv = (off <= ws_size);

    if (preconv) {
        k_cast<<<dim3(2048), dim3(256), 0, stream>>>((const float4*)Wqkv, (ushort4*)WqkvB, (int)(nWqkv / 4));
        k_cast<<<dim3(2048), dim3(256), 0, stream>>>((const float4*)Wout, (ushort4*)WoutB, (int)(nWout / 4));
        k_cast<<<dim3(2048), dim3(256), 0, stream>>>((const float4*)W1,   (ushort4*)W1B,   (int)(nW1 / 4));
        k_cast<<<dim3(2048), dim3(256), 0, stream>>>((const float4*)W2,   (ushort4*)W2B,   (int)(nW2 / 4));
        k_cast<<<dim3(2048), dim3(256), 0, stream>>>((const float4*)lmh,  (ushort4*)lmhB,  (int)(nLmh / 4));
    }

#define LAUNCH_GEMM(BN, EPI, OUTBF, SPLITK, GX, GY, GZ, Aq, Wb16, Wf32, Cq, Rq, Mv, Nv, Kv)  \
    do {                                                                                     \
        if (preconv)                                                                         \
            k_mfma_gemm<BN, EPI, OUTBF, false, SPLITK><<<dim3(GX, GY, GZ), dim3(256), 0, stream>>>( \
                (const ushort*)(Aq), (const void*)(Wb16), (void*)(Cq), (Rq), cosT, sinT,     \
                Mv, Nv, Kv);                                                                 \
        else                                                                                 \
            k_mfma_gemm<BN, EPI, OUTBF, true, SPLITK><<<dim3(GX, GY, GZ), dim3(256), 0, stream>>>( \
                (const ushort*)(Aq), (const void*)(Wf32), (void*)(Cq), (Rq), cosT, sinT,     \
                Mv, Nv, Kv);                                                                 \
    } while (0)

    k_rope_tables<<<dim3(T_), dim3(32), 0, stream>>>(cosT, sinT);
    k_gather<<<dim3(NT), dim3(256), 0, stream>>>(xi, emb, xbuf);

    for (int l = 0; l < L_; l++) {
        k_rmsnorm<<<dim3(NT), dim3(256), 0, stream>>>(xbuf, nb);
        LAUNCH_GEMM(128, 3, true, false, 16, 24, 1, nb,
                    WqkvB + (size_t)l * 3 * D_ * D_, Wqkv + (size_t)l * 3 * D_ * D_,
                    qkv, nullptr, (int)NT, 3 * D_, D_);
        k_attn_p8<<<dim3(8, B_ * H_), dim3(512), 0, stream>>>(qkv, ctxb);
        LAUNCH_GEMM(64, 4, false, true, 16, 16, 2, ctxb,
                    WoutB + (size_t)l * D_ * D_, Wout + (size_t)l * D_ * D_,
                    xbuf, nullptr, (int)NT, D_, D_);
        k_rmsnorm<<<dim3(NT), dim3(256), 0, stream>>>(xbuf, nb);
        LAUNCH_GEMM(256, 2, true, false, 16, 16, 1, nb,
                    W1B + (size_t)l * 4 * D_ * D_, W1 + (size_t)l * 4 * D_ * D_,
                    hb, nullptr, (int)NT, 4 * D_, D_);
        LAUNCH_GEMM(64, 4, false, true, 16, 16, 2, hb,
                    W2B + (size_t)l * 4 * D_ * D_, W2 + (size_t)l * 4 * D_ * D_,
                    xbuf, nullptr, (int)NT, D_, 4 * D_);
    }
    k_rmsnorm<<<dim3(NT), dim3(256), 0, stream>>>(xbuf, nb);
    if (preconv)
        k_gemm256c<<<dim3(8, 125), dim3(512), 0, stream>>>(nb, lmhB, out, (int)NT, V_, D_);
    else
        LAUNCH_GEMM(256, 0, false, false, 16, 125, 1, nb, lmhB, lmh, out, nullptr, (int)NT, V_, D_);
#undef LAUNCH_GEMM
}

// Round 17
// 1733.738 us; speedup vs baseline: 1.1294x; 1.0004x over previous
//
#include <hip/hip_runtime.h>
#include <hip/hip_bf16.h>
#include <cmath>
#include <cstdint>

#define B_  2
#define T_  1024
#define V_  32000
#define D_  1024
#define H_  16
#define L_  8
#define DH_ 64

typedef __attribute__((ext_vector_type(8))) short bf16x8;
typedef __attribute__((ext_vector_type(4))) float f32x4;

__device__ __forceinline__ ushort f2bf(float f) {
    union { float f; uint32_t u; } v; v.f = f;
    uint32_t r = v.u + 0x7FFFu + ((v.u >> 16) & 1u);
    return (ushort)(r >> 16);
}
__device__ __forceinline__ float bf2f(ushort u) {
    union { uint32_t u; float f; } v; v.u = ((uint32_t)u) << 16;
    return v.f;
}

__device__ __forceinline__ void async_copy16(const void* g, void* l) {
    __builtin_amdgcn_global_load_lds(
        (const __attribute__((address_space(1))) void*)g,
        (__attribute__((address_space(3))) void*)l, 16, 0, 0);
}

// ---------------- fp32 -> bf16 cast, all 5 weight tensors in one launch ----------------
// dst regions are contiguous carves in ws (each a multiple of 256 B).
__global__ __launch_bounds__(256) void k_cast5(const float4* __restrict__ s0,
                                               const float4* __restrict__ s1,
                                               const float4* __restrict__ s2,
                                               const float4* __restrict__ s3,
                                               const float4* __restrict__ s4,
                                               ushort4* __restrict__ out,
                                               int c0, int c1, int c2, int c3, int c4) {
    const int total = c0 + c1 + c2 + c3 + c4;
    for (int i = blockIdx.x * 256 + threadIdx.x; i < total; i += gridDim.x * 256) {
        const float4* src; int j = i;
        if (j < c0) src = s0;
        else { j -= c0; if (j < c1) src = s1;
        else { j -= c1; if (j < c2) src = s2;
        else { j -= c2; if (j < c3) src = s3;
        else { j -= c3; src = s4; } } } }
        float4 v = src[j];
        out[i] = make_ushort4(f2bf(v.x), f2bf(v.y), f2bf(v.z), f2bf(v.w));
    }
}

// ---------------- RoPE tables: cos/sin (T, 32) ----------------
__global__ void k_rope_tables(float* __restrict__ cosT, float* __restrict__ sinT) {
    int t = blockIdx.x;
    int i = threadIdx.x;           // 0..31
    float invf = (i < 16) ? powf(1000.0f, -(float)i / 16.0f) : 0.0f;
    float th = (float)t * invf;
    cosT[t * 32 + i] = cosf(th);
    sinT[t * 32 + i] = sinf(th);
}

// ---------------- Embedding gather (fp32 x) ----------------
__global__ __launch_bounds__(256) void k_gather(const int* __restrict__ idx,
                                                const float* __restrict__ emb,
                                                float* __restrict__ x) {
    int row = blockIdx.x;
    int id = idx[row];
    const float4* src = (const float4*)(emb + (size_t)id * D_);
    float4* dst = (float4*)(x + (size_t)row * D_);
    dst[threadIdx.x] = src[threadIdx.x];
}

// ---------------- RMSNorm: bf16 out ----------------
__global__ __launch_bounds__(256) void k_rmsnorm(const float* __restrict__ x,
                                                 ushort* __restrict__ out) {
    int row = blockIdx.x;
    const float4* xr = (const float4*)(x + (size_t)row * D_);
    float4 v = xr[threadIdx.x];
    float ss = v.x * v.x + v.y * v.y + v.z * v.z + v.w * v.w;
    #pragma unroll
    for (int off = 1; off < 64; off <<= 1) ss += __shfl_xor(ss, off);
    __shared__ float wsum[4];
    int lane = threadIdx.x & 63, wv = threadIdx.x >> 6;
    if (lane == 0) wsum[wv] = ss;
    __syncthreads();
    float tot = wsum[0] + wsum[1] + wsum[2] + wsum[3];
    float inv = rsqrtf(tot * (1.0f / D_) + 1e-6f);
    ushort4 r = make_ushort4(f2bf(v.x * inv), f2bf(v.y * inv), f2bf(v.z * inv), f2bf(v.w * inv));
    *(ushort4*)(out + (size_t)row * D_ + threadIdx.x * 4) = r;
}

// ---------------- MFMA GEMM: BM=128, BK=64, T2 swizzle, T1 swizzle ----------------
// BN<=128: prefetch double-buffer. BN=256: single buffer, high-intensity tile.
// Split-K via gridDim.z: each z-block accumulates K/gridDim.z (use with EPI=4).
// EPI: 0 none(+nontemporal), 1 +Res(fp32), 2 relu^2, 3 RoPE(qkv), 4 atomicAdd(fp32).
template<int BN, int EPI, bool OUTBF, bool CONVB>
__global__ __launch_bounds__(256, 2) void k_mfma_gemm(const ushort* __restrict__ A,
                                                      const void* __restrict__ Wp,
                                                      void* __restrict__ Cp,
                                                      const float* __restrict__ Res,
                                                      const float* __restrict__ cosT,
                                                      const float* __restrict__ sinT,
                                                      int M, int N, int K) {
    constexpr int BM = 128;
    constexpr int MI = 4;
    constexpr int NI = BN / 32;
    constexpr bool DBUF = (BN <= 128);
    constexpr int NB = DBUF ? 2 : 1;
    __shared__ ushort As[NB][BM][64];   // swizzled: chunk c of row r at byte ((c^(r&7))<<4)
    __shared__ ushort Bs[NB][BN][64];
    const int tid = threadIdx.x;
    const int wid = tid >> 6, lane = tid & 63;
    const int wr = wid >> 1, wc = wid & 1;
    const int r16 = lane & 15, kc = lane >> 4;
    const int rx = (r16 & 7) << 4;
    const int srow8 = tid >> 3;
    const int sdcp = tid & 7;

    const int nwg = gridDim.x * gridDim.y;
    int orig = blockIdx.y * gridDim.x + blockIdx.x;
    int swz = (nwg & 7) ? orig : ((orig & 7) * (nwg >> 3) + (orig >> 3));
    const size_t bm = (size_t)(swz % gridDim.x) * BM;
    const size_t bn = (size_t)(swz / gridDim.x) * BN;

    const int Kz = K / (int)gridDim.z;
    const int KSTEPS = Kz >> 6;
    const int kbase = (int)blockIdx.z * Kz;

    auto stage = [&](int buf, int k0) {
        #pragma unroll
        for (int i = 0; i < 4; i++) {
            const int row = i * 32 + srow8;
            const ushort* g = A + (bm + row) * (size_t)K + k0 + ((sdcp ^ (row & 7)) * 8);
            async_copy16(g, (char*)As + buf * (BM * 128) + (i * 256 + tid) * 16);
        }
        if constexpr (!CONVB) {
            const ushort* Wb = (const ushort*)Wp;
            #pragma unroll
            for (int i = 0; i < BN / 32; i++) {
                const int row = i * 32 + srow8;
                const ushort* g = Wb + (bn + row) * (size_t)K + k0 + ((sdcp ^ (row & 7)) * 8);
                async_copy16(g, (char*)Bs + buf * (BN * 128) + (i * 256 + tid) * 16);
            }
        } else {
            const float* Wf = (const float*)Wp;
            #pragma unroll
            for (int i = 0; i < BN / 32; i++) {
                const int row = i * 32 + srow8;
                const float* src = Wf + (bn + row) * (size_t)K + k0 + sdcp * 8;
                float4 v0 = *(const float4*)(src);
                float4 v1 = *(const float4*)(src + 4);
                union { ushort u[8]; bf16x8 v; } tmp;
                tmp.u[0] = f2bf(v0.x); tmp.u[1] = f2bf(v0.y);
                tmp.u[2] = f2bf(v0.z); tmp.u[3] = f2bf(v0.w);
                tmp.u[4] = f2bf(v1.x); tmp.u[5] = f2bf(v1.y);
                tmp.u[6] = f2bf(v1.z); tmp.u[7] = f2bf(v1.w);
                *(bf16x8*)((char*)Bs + buf * (BN * 128) + row * 128 + ((sdcp ^ (row & 7)) << 4)) = tmp.v;
            }
        }
    };

    f32x4 acc[MI][NI];
    #pragma unroll
    for (int mi = 0; mi < MI; mi++)
        #pragma unroll
        for (int ni = 0; ni < NI; ni++) {
            f32x4 z = {0.f, 0.f, 0.f, 0.f};
            acc[mi][ni] = z;
        }

    auto compute = [&](int buf) {
        #pragma unroll
        for (int kk = 0; kk < 2; kk++) {
            bf16x8 af[MI], bfr[NI];
            #pragma unroll
            for (int mi = 0; mi < MI; mi++)
                af[mi] = *(const bf16x8*)((const char*)As + buf * (BM * 128) +
                                          (wr * 64 + mi * 16 + r16) * 128 +
                                          ((kk * 64 + kc * 16) ^ rx));
            #pragma unroll
            for (int ni = 0; ni < NI; ni++)
                bfr[ni] = *(const bf16x8*)((const char*)Bs + buf * (BN * 128) +
                                           (wc * (BN / 2) + ni * 16 + r16) * 128 +
                                           ((kk * 64 + kc * 16) ^ rx));
            #pragma unroll
            for (int mi = 0; mi < MI; mi++)
                #pragma unroll
                for (int ni = 0; ni < NI; ni++)
                    acc[mi][ni] = __builtin_amdgcn_mfma_f32_16x16x32_bf16(af[mi], bfr[ni],
                                                                          acc[mi][ni], 0, 0, 0);
        }
    };

    if constexpr (DBUF) {
        stage(0, kbase);
        __syncthreads();
        for (int step = 0; step < KSTEPS; ++step) {
            const int cur = step & 1;
            if (step + 1 < KSTEPS) stage(cur ^ 1, kbase + ((step + 1) << 6));
            compute(cur);
            __syncthreads();
        }
    } else {
        for (int step = 0; step < KSTEPS; ++step) {
            stage(0, kbase + (step << 6));
            __syncthreads();
            compute(0);
            __syncthreads();
        }
    }

    #pragma unroll
    for (int mi = 0; mi < MI; mi++) {
        #pragma unroll
        for (int j = 0; j < 4; j++) {
            const size_t row = bm + wr * 64 + mi * 16 + (lane >> 4) * 4 + j;
            if constexpr (EPI == 3) {
                static_assert(BN == 128, "rope epilogue assumes BN=128");
                const int sec = (int)((bn + wc * 64) >> 10);   // 0=q,1=k,2=v
                if (sec < 2) {
                    const int t = (int)(row & (T_ - 1));
                    #pragma unroll
                    for (int np = 0; np < 2; np++) {
                        const int i1 = np * 16 + r16;          // 0..31
                        float c = cosT[t * 32 + i1], s = sinT[t * 32 + i1];
                        float x1 = acc[mi][np][j], x2 = acc[mi][np + 2][j];
                        acc[mi][np][j]     = c * x1 - s * x2;
                        acc[mi][np + 2][j] = s * x1 + c * x2;
                    }
                }
            }
            #pragma unroll
            for (int ni = 0; ni < NI; ni++) {
                const size_t col = bn + wc * (BN / 2) + ni * 16 + r16;
                float v = acc[mi][ni][j];
                if constexpr (EPI == 1) v += Res[row * N + col];
                if constexpr (EPI == 2) { v = fmaxf(v, 0.f); v *= v; }
                if constexpr (EPI == 4) {
                    atomicAdd((float*)Cp + row * N + col, v);
                } else if constexpr (OUTBF) {
                    ((ushort*)Cp)[row * N + col] = f2bf(v);
                } else if constexpr (EPI == 0) {
                    __builtin_nontemporal_store(v, (float*)Cp + row * N + col);
                } else {
                    ((float*)Cp)[row * N + col] = v;
                }
            }
        }
    }
}

// ---------------- 256x256 8-wave GEMM with half-tile counted-vmcnt pipeline (lm_head) ----------------
__global__ __launch_bounds__(512, 2) void k_gemm256c(const ushort* __restrict__ A,
                                                     const ushort* __restrict__ Wb,
                                                     float* __restrict__ C,
                                                     int M, int N, int K) {
    __shared__ __align__(16) char lds[131072];   // [buf 64KB][part 16KB]
    const int tid = threadIdx.x;
    const int wid = tid >> 6, lane = tid & 63;
    const int wr = wid >> 2, wc = wid & 3;       // 2 x 4 wave grid
    const int r16 = lane & 15, kc = lane >> 4;
    const int rx = (r16 & 7) << 4;

    const int nwg = gridDim.x * gridDim.y;
    int orig = blockIdx.y * gridDim.x + blockIdx.x;
    int swz = (nwg & 7) ? orig : ((orig & 7) * (nwg >> 3) + (orig >> 3));
    const size_t bm = (size_t)(swz % gridDim.x) * 256;
    const size_t bn = (size_t)(swz / gridDim.x) * 256;

    // part: 0=PA0, 1=PA1 (row bit6 split), 2=PB0, 3=PB1 (row bit5 split)
    auto stagep = [&](int buf, int part, int k0) {
        #pragma unroll
        for (int i = 0; i < 2; i++) {
            const int s = i * 512 + tid;
            const int sr = s >> 3, ch = s & 7;
            const int gcol = (ch ^ (sr & 7)) * 8;
            int grow;
            const ushort* base;
            if (part < 2) {
                grow = (sr >> 6) * 128 + part * 64 + (sr & 63);
                base = A + (bm + grow) * (size_t)K;
            } else {
                grow = (sr >> 5) * 64 + (part - 2) * 32 + (sr & 31);
                base = Wb + (bn + grow) * (size_t)K;
            }
            async_copy16(base + k0 + gcol, lds + buf * 65536 + part * 16384 + s * 16);
        }
    };

    f32x4 acc[8][4];
    #pragma unroll
    for (int mi = 0; mi < 8; mi++)
        #pragma unroll
        for (int ni = 0; ni < 4; ni++) {
            f32x4 z = {0.f, 0.f, 0.f, 0.f};
            acc[mi][ni] = z;
        }

    bf16x8 af[4][2], bfA[2][2], bfB[2][2];
    auto loadA_ = [&](int buf, int mh) {
        #pragma unroll
        for (int q = 0; q < 4; q++)
            #pragma unroll
            for (int kk = 0; kk < 2; kk++)
                af[q][kk] = *(const bf16x8*)(lds + buf * 65536 + mh * 16384 +
                                             (wr * 64 + q * 16 + r16) * 128 +
                                             ((kk * 64 + kc * 16) ^ rx));
    };
    auto loadB_ = [&](int buf, int nh, bf16x8 (&bf)[2][2]) {
        #pragma unroll
        for (int r = 0; r < 2; r++)
            #pragma unroll
            for (int kk = 0; kk < 2; kk++)
                bf[r][kk] = *(const bf16x8*)(lds + buf * 65536 + 32768 + nh * 16384 +
                                             (wc * 32 + r * 16 + r16) * 128 +
                                             ((kk * 64 + kc * 16) ^ rx));
    };
    auto quad = [&](int mh, int nh, bf16x8 (&bf)[2][2]) {
        __builtin_amdgcn_s_setprio(1);
        #pragma unroll
        for (int kk = 0; kk < 2; kk++)
            #pragma unroll
            for (int q = 0; q < 4; q++)
                #pragma unroll
                for (int r = 0; r < 2; r++)
                    acc[mh * 4 + q][nh * 2 + r] =
                        __builtin_amdgcn_mfma_f32_16x16x32_bf16(af[q][kk], bf[r][kk],
                                                                acc[mh * 4 + q][nh * 2 + r], 0, 0, 0);
        __builtin_amdgcn_s_setprio(0);
    };

    const int KS = K >> 6;   // 16
    stagep(0, 0, 0); stagep(0, 2, 0); stagep(0, 3, 0); stagep(0, 1, 0);

    for (int t = 0; t < KS; ++t) {
        const int cur = t & 1, nxt = cur ^ 1;
        const bool pre = (t + 1 < KS);
        const int k1 = (t + 1) << 6;
        asm volatile("s_waitcnt vmcnt(4)" ::: "memory");
        asm volatile("s_barrier" ::: "memory");
        if (pre) stagep(nxt, 0, k1);
        loadA_(cur, 0); loadB_(cur, 0, bfA);
        quad(0, 0, bfA);
        if (pre) asm volatile("s_waitcnt vmcnt(4)" ::: "memory");
        else     asm volatile("s_waitcnt vmcnt(2)" ::: "memory");
        asm volatile("s_barrier" ::: "memory");
        if (pre) stagep(nxt, 2, k1);
        loadB_(cur, 1, bfB);
        quad(0, 1, bfB);
        if (pre) asm volatile("s_waitcnt vmcnt(4)" ::: "memory");
        else     asm volatile("s_waitcnt vmcnt(0)" ::: "memory");
        asm volatile("s_barrier" ::: "memory");
        if (pre) stagep(nxt, 3, k1);
        loadA_(cur, 1);
        quad(1, 1, bfB);
        if (pre) stagep(nxt, 1, k1);
        quad(1, 0, bfA);
    }

    #pragma unroll
    for (int mi = 0; mi < 8; mi++) {
        #pragma unroll
        for (int j = 0; j < 4; j++) {
            const size_t row = bm + wr * 128 + mi * 16 + (lane >> 4) * 4 + j;
            #pragma unroll
            for (int ni = 0; ni < 4; ni++) {
                const size_t col = bn + wc * 64 + ni * 16 + r16;
                __builtin_nontemporal_store(acc[mi][ni][j], C + row * (size_t)N + col);
            }
        }
    }
}

// ---------------- 8-wave paired flash attention, KVBLK=128 (R13, best) ----------------
__global__ __launch_bounds__(512) void k_attn_p8(const ushort* __restrict__ qkv,
                                                 ushort* __restrict__ ctx) {
    __shared__ __align__(16) char lds[65536];
    const int tid = threadIdx.x;
    const int w = tid >> 6, lane = tid & 63;
    const int r16 = lane & 15, kc = lane >> 4;
    const int rx = (r16 & 7) << 4;
    const int ip = blockIdx.x;                 // 0..7
    const int tw = w >> 2;                     // 0 = hi tile, 1 = lo tile
    const int wq = w & 3;
    const int hib = (15 - ip) * 64, lob = ip * 64;
    const int tb = tw ? lob : hib;
    const int pq = 32768 + tw * 16384;
    const int bh = blockIdx.y, b = bh >> 4, h = bh & 15;
    const size_t tok0 = (size_t)b * T_;
    const ushort* kg = qkv + tok0 * (3 * D_) + D_ + h * DH_;
    const ushort* vg = qkv + tok0 * (3 * D_) + 2 * D_ + h * DH_;
    const float SCALE_LOG2E = 0.125f * 1.44269504089f;

    {
        const int bases[2] = { hib, lob };
        #pragma unroll
        for (int t = 0; t < 2; t++) {
            const int row = tid >> 3, dcp = tid & 7;
            const int d0 = (dcp ^ (row & 7)) * 8;
            const ushort* qg = qkv + (tok0 + bases[t] + row) * (3 * D_) + h * DH_ + d0;
            async_copy16(qg, lds + 32768 + t * 16384 + tid * 16);
        }
    }
    __syncthreads();
    bf16x8 aq[2];
    #pragma unroll
    for (int ks = 0; ks < 2; ks++) {
        const int row = wq * 16 + r16;
        aq[ks] = *(const bf16x8*)(lds + pq + row * 128 + ((ks * 64 + kc * 16) ^ rx));
    }

    f32x4 o[4];
    float m[4], l[4], corr[4];
    #pragma unroll
    for (int nd = 0; nd < 4; nd++) { f32x4 z = {0.f, 0.f, 0.f, 0.f}; o[nd] = z; }
    #pragma unroll
    for (int j = 0; j < 4; j++) { m[j] = -1e30f; l[j] = 0.f; }

    const int nchunks = (17 - ip) >> 1;
    for (int ch = 0; ch < nchunks; ch++) {
        const int kb = ch << 7;
        __syncthreads();
        #pragma unroll
        for (int i = 0; i < 2; i++) {
            const int slot = i * 512 + tid;
            const int row = slot >> 3, dcp = slot & 7;
            const int d0 = (dcp ^ (row & 7)) * 8;
            async_copy16(kg + (size_t)(kb + row) * (3 * D_) + d0, lds + slot * 16);
        }
        {
            const int key = tid >> 2, dbase = (tid & 3) * 16;
            const ushort* src = vg + (size_t)(kb + key) * (3 * D_) + dbase;
            bf16x8 v0 = *(const bf16x8*)(src);
            bf16x8 v1 = *(const bf16x8*)(src + 8);
            #pragma unroll
            for (int e = 0; e < 8; e++) {
                int d = dbase + e;
                *(ushort*)(lds + 16384 + d * 256 + ((key * 2) ^ ((d & 7) << 4))) = (ushort)v0[e];
                d = dbase + 8 + e;
                *(ushort*)(lds + 16384 + d * 256 + ((key * 2) ^ ((d & 7) << 4))) = (ushort)v1[e];
            }
        }
        __syncthreads();

        const bool active = (tw == 0) || (kb < lob + 64);
        if (active) {
            f32x4 s[8];
            #pragma unroll
            for (int ni = 0; ni < 8; ni++) { f32x4 z = {0.f, 0.f, 0.f, 0.f}; s[ni] = z; }
            __builtin_amdgcn_s_setprio(1);
            #pragma unroll
            for (int ks = 0; ks < 2; ks++)
                #pragma unroll
                for (int ni = 0; ni < 8; ni++) {
                    const int row = ni * 16 + r16;
                    bf16x8 kf = *(const bf16x8*)(lds + row * 128 + ((ks * 64 + kc * 16) ^ rx));
                    s[ni] = __builtin_amdgcn_mfma_f32_16x16x32_bf16(aq[ks], kf, s[ni], 0, 0, 0);
                }
            __builtin_amdgcn_s_setprio(0);

            const bool needmask = (kb + 127 > tb);
            #pragma unroll
            for (int j = 0; j < 4; j++) {
                const int qrow = tb + wq * 16 + kc * 4 + j;
                #pragma unroll
                for (int ni = 0; ni < 8; ni++) {
                    float v = s[ni][j] * SCALE_LOG2E;
                    if (needmask) { int key = kb + ni * 16 + r16; if (key > qrow) v = -1e30f; }
                    s[ni][j] = v;
                }
                float t0 = fmaxf(fmaxf(s[0][j], s[1][j]), fmaxf(s[2][j], s[3][j]));
                float t1 = fmaxf(fmaxf(s[4][j], s[5][j]), fmaxf(s[6][j], s[7][j]));
                float tmax = fmaxf(t0, t1);
                #pragma unroll
                for (int off = 1; off < 16; off <<= 1) tmax = fmaxf(tmax, __shfl_xor(tmax, off));
                const float mn = fmaxf(m[j], tmax);
                corr[j] = exp2f(m[j] - mn);
                m[j] = mn;
                float ps = 0.f;
                #pragma unroll
                for (int ni = 0; ni < 8; ni++) {
                    float p = exp2f(s[ni][j] - mn);
                    s[ni][j] = p;
                    ps += p;
                }
                #pragma unroll
                for (int off = 1; off < 16; off <<= 1) ps += __shfl_xor(ps, off);
                l[j] = l[j] * corr[j] + ps;
            }
            #pragma unroll
            for (int ni = 0; ni < 8; ni++)
                #pragma unroll
                for (int j = 0; j < 4; j++) {
                    const int row = wq * 16 + kc * 4 + j;
                    *(ushort*)(lds + pq + row * 256 + ((ni * 32 + r16 * 2) ^ ((row & 7) << 4))) = f2bf(s[ni][j]);
                }
            #pragma unroll
            for (int nd = 0; nd < 4; nd++)
                #pragma unroll
                for (int j = 0; j < 4; j++) o[nd][j] *= corr[j];
            __builtin_amdgcn_s_setprio(1);
            #pragma unroll
            for (int ks = 0; ks < 4; ks++) {
                const int prow = wq * 16 + r16;
                bf16x8 pf = *(const bf16x8*)(lds + pq + prow * 256 + ((ks * 64 + kc * 16) ^ rx));
                #pragma unroll
                for (int nd = 0; nd < 4; nd++) {
                    const int drow = nd * 16 + r16;
                    bf16x8 vf = *(const bf16x8*)(lds + 16384 + drow * 256 + ((ks * 64 + kc * 16) ^ rx));
                    o[nd] = __builtin_amdgcn_mfma_f32_16x16x32_bf16(pf, vf, o[nd], 0, 0, 0);
                }
            }
            __builtin_amdgcn_s_setprio(0);
        }
    }

    #pragma unroll
    for (int j = 0; j < 4; j++) {
        const float inv = 1.0f / l[j];
        const int row = tb + wq * 16 + kc * 4 + j;
        ushort* dst = ctx + (tok0 + row) * D_ + h * DH_;
        #pragma unroll
        for (int nd = 0; nd < 4; nd++)
            dst[nd * 16 + r16] = f2bf(o[nd][j] * inv);
    }
}

extern "C" void kernel_launch(void* const* d_in, const int* in_sizes, int n_in,
                              void* d_out, int out_size, void* d_ws, size_t ws_size,
                              hipStream_t stream) {
    const int*   xi   = (const int*)d_in[0];
    const float* emb  = (const float*)d_in[1];
    const float* Wqkv = (const float*)d_in[2];
    const float* Wout = (const float*)d_in[3];
    const float* W1   = (const float*)d_in[4];
    const float* W2   = (const float*)d_in[5];
    const float* lmh  = (const float*)d_in[6];
    float* out = (float*)d_out;

    const size_t NT = (size_t)B_ * T_;
    size_t off = 0;
    auto carve = [&](size_t bytes) -> char* {
        char* r = (char*)d_ws + off;
        off += (bytes + 255) & ~(size_t)255;
        return r;
    };
    float*  xbuf = (float*)carve(NT * D_ * 4);
    ushort* qkv  = (ushort*)carve(NT * 3 * D_ * 2);
    ushort* nb   = (ushort*)carve(NT * D_ * 2);
    ushort* ctxb = (ushort*)carve(NT * D_ * 2);
    ushort* hb   = (ushort*)carve(NT * 4 * D_ * 2);
    float*  cosT = (float*)carve(T_ * 32 * 4);
    float*  sinT = (float*)carve(T_ * 32 * 4);

    const size_t nWqkv = (size_t)L_ * 3 * D_ * D_;
    const size_t nWout = (size_t)L_ * D_ * D_;
    const size_t nW1   = (size_t)L_ * 4 * D_ * D_;
    const size_t nW2   = (size_t)L_ * 4 * D_ * D_;
    const size_t nLmh  = (size_t)V_ * D_;
    ushort* WqkvB = (ushort*)carve(nWqkv * 2);   // contiguous with the next four
    ushort* WoutB = (ushort*)carve(nWout * 2);
    ushort* W1B   = (ushort*)carve(nW1 * 2);
    ushort* W2B   = (ushort*)carve(nW2 * 2);
    ushort* lmhB  = (ushort*)carve(nLmh * 2);
    const bool preconv = (off <= ws_size);

    if (preconv) {
        k_cast5<<<dim3(4096), dim3(256), 0, stream>>>(
            (const float4*)Wqkv, (const float4*)Wout, (const float4*)W1,
            (const float4*)W2, (const float4*)lmh, (ushort4*)WqkvB,
            (int)(nWqkv / 4), (int)(nWout / 4), (int)(nW1 / 4),
            (int)(nW2 / 4), (int)(nLmh / 4));
    }

#define LAUNCH_GEMM(BN, EPI, OUTBF, GX, GY, GZ, Aq, Wb16, Wf32, Cq, Rq, Mv, Nv, Kv)          \
    do {                                                                                     \
        if (preconv)                                                                         \
            k_mfma_gemm<BN, EPI, OUTBF, false><<<dim3(GX, GY, GZ), dim3(256), 0, stream>>>(  \
                (const ushort*)(Aq), (const void*)(Wb16), (void*)(Cq), (Rq), cosT, sinT,     \
                Mv, Nv, Kv);                                                                 \
        else                                                                                 \
            k_mfma_gemm<BN, EPI, OUTBF, true><<<dim3(GX, GY, GZ), dim3(256), 0, stream>>>(   \
                (const ushort*)(Aq), (const void*)(Wf32), (void*)(Cq), (Rq), cosT, sinT,     \
                Mv, Nv, Kv);                                                                 \
    } while (0)

    k_rope_tables<<<dim3(T_), dim3(32), 0, stream>>>(cosT, sinT);
    k_gather<<<dim3(NT), dim3(256), 0, stream>>>(xi, emb, xbuf);

    for (int l = 0; l < L_; l++) {
        k_rmsnorm<<<dim3(NT), dim3(256), 0, stream>>>(xbuf, nb);
        // qkv = rope(n * Wqkv^T), bf16
        LAUNCH_GEMM(128, 3, true, 16, 24, 1, nb,
                    WqkvB + (size_t)l * 3 * D_ * D_, Wqkv + (size_t)l * 3 * D_ * D_,
                    qkv, nullptr, (int)NT, 3 * D_, D_);
        k_attn_p8<<<dim3(8, B_ * H_), dim3(512), 0, stream>>>(qkv, ctxb);
        // x += ctx * Wout^T  (split-K=2, atomicAdd into xbuf)
        LAUNCH_GEMM(64, 4, false, 16, 16, 2, ctxb,
                    WoutB + (size_t)l * D_ * D_, Wout + (size_t)l * D_ * D_,
                    xbuf, nullptr, (int)NT, D_, D_);
        k_rmsnorm<<<dim3(NT), dim3(256), 0, stream>>>(xbuf, nb);
        // h = relu(n * W1^T)^2, bf16  (BN=256 high-intensity tile)
        LAUNCH_GEMM(256, 2, true, 16, 16, 1, nb,
                    W1B + (size_t)l * 4 * D_ * D_, W1 + (size_t)l * 4 * D_ * D_,
                    hb, nullptr, (int)NT, 4 * D_, D_);
        // x += h * W2^T  (BN=128, split-K=4: 512 blocks, 16 MFMA/step, 16 K-steps)
        LAUNCH_GEMM(128, 4, false, 16, 8, 4, hb,
                    W2B + (size_t)l * 4 * D_ * D_, W2 + (size_t)l * 4 * D_ * D_,
                    xbuf, nullptr, (int)NT, D_, 4 * D_);
    }
    k_rmsnorm<<<dim3(NT), dim3(256), 0, stream>>>(xbuf, nb);
    if (preconv)
        k_gemm256c<<<dim3(8, 125), dim3(512), 0, stream>>>(nb, lmhB, out, (int)NT, V_, D_);
    else
        LAUNCH_GEMM(256, 0, false, 16, 125, 1, nb, lmhB, lmh, out, nullptr, (int)NT, V_, D_);
#undef LAUNCH_GEMM
}